// Round 1
// baseline (7144.514 us; speedup 1.0000x reference)
//
#include <hip/hip_runtime.h>
#include <math.h>

#define FEAT 128

__device__ __forceinline__ float eluf(float x) {
  return x > 0.0f ? x : (__expf(x) - 1.0f);
}
__device__ __forceinline__ float lreluf(float x) {
  return x > 0.0f ? x : 0.2f * x;
}
// order-preserving float->uint map for atomicMax on signed floats
__device__ __forceinline__ unsigned flipf(float f) {
  unsigned u = __float_as_uint(f);
  return (u & 0x80000000u) ? ~u : (u | 0x80000000u);
}
__device__ __forceinline__ float unflipf(unsigned u) {
  return __uint_as_float((u & 0x80000000u) ? (u ^ 0x80000000u) : ~u);
}

// zero acc [nacc4 float4], mkey/denom [nmd4 x4]
__global__ __launch_bounds__(256) void zero_kernel(float4* __restrict__ acc,
                                                   uint4* __restrict__ mkey,
                                                   float4* __restrict__ denom,
                                                   int nacc4, int nmd4) {
  const int stride = gridDim.x * blockDim.x;
  const float4 z = make_float4(0.f, 0.f, 0.f, 0.f);
  const uint4 zu = make_uint4(0u, 0u, 0u, 0u);
  for (int i = blockIdx.x * blockDim.x + threadIdx.x; i < nacc4; i += stride) acc[i] = z;
  for (int i = blockIdx.x * blockDim.x + threadIdx.x; i < nmd4; i += stride) {
    mkey[i] = zu;
    denom[i] = z;
  }
}

// h = transform(in) @ W ; also alpha_s/alpha_d epilogue.
// transform = elu(x + tb) when tb != nullptr (folds previous layer's bias+ELU).
// Block: 256 threads. Tile: 16 rows x 128 cols. Thread: j = t&127, 8 rows.
__global__ __launch_bounds__(256, 2) void gemm_kernel(
    const float* __restrict__ in, const float* __restrict__ W,
    const float* __restrict__ tb,
    const float* __restrict__ avs, const float* __restrict__ avd,
    float* __restrict__ hout, float* __restrict__ as_out, float* __restrict__ ad_out,
    int n) {
  __shared__ float Wl[128 * 128];
  __shared__ float xl[16][128];
  __shared__ float asl[128];
  __shared__ float adl[128];
  const int t = threadIdx.x;

  // stage W (row-major [k][j]) : 4096 float4, 16 per thread, coalesced
  for (int c = 0; c < 16; ++c) {
    int id = c * 256 + t;
    *(float4*)&Wl[id * 4] = *(const float4*)&W[id * 4];
  }
  if (t < 128) { asl[t] = avs[t]; adl[t] = avd[t]; }
  __syncthreads();

  const int j = t & 127;
  const int rg = t >> 7;  // 0..1, 8 rows each
  const float asv = asl[j];
  const float adv = adl[j];
  const int head = j >> 5;
  const int ntiles = (n + 15) >> 4;

  for (int tile = blockIdx.x; tile < ntiles; tile += gridDim.x) {
    const int r0 = tile << 4;
    // stage 16 rows (512 float4, 2 per thread), with optional elu(x+b) transform
    for (int c = 0; c < 2; ++c) {
      int id = c * 256 + t;          // [0,512)
      int r = id >> 5;               // row within tile
      int k4 = (id & 31) * 4;
      int row = r0 + r;
      float4 v = make_float4(0.f, 0.f, 0.f, 0.f);
      if (row < n) {
        v = *(const float4*)&in[row * FEAT + k4];
        if (tb) {
          v.x = eluf(v.x + tb[k4 + 0]);
          v.y = eluf(v.y + tb[k4 + 1]);
          v.z = eluf(v.z + tb[k4 + 2]);
          v.w = eluf(v.w + tb[k4 + 3]);
        }
      }
      *(float4*)&xl[r][k4] = v;
    }
    __syncthreads();

    float acc[8];
#pragma unroll
    for (int r = 0; r < 8; ++r) acc[r] = 0.f;

    for (int k4 = 0; k4 < 128; k4 += 4) {
      const float w0 = Wl[(k4 + 0) * 128 + j];
      const float w1 = Wl[(k4 + 1) * 128 + j];
      const float w2 = Wl[(k4 + 2) * 128 + j];
      const float w3 = Wl[(k4 + 3) * 128 + j];
#pragma unroll
      for (int r = 0; r < 8; ++r) {
        float4 xv = *(const float4*)&xl[rg * 8 + r][k4];
        acc[r] = fmaf(xv.x, w0, acc[r]);
        acc[r] = fmaf(xv.y, w1, acc[r]);
        acc[r] = fmaf(xv.z, w2, acc[r]);
        acc[r] = fmaf(xv.w, w3, acc[r]);
      }
    }

    // write h + alpha epilogue (reduce over 32-lane head groups)
#pragma unroll
    for (int r = 0; r < 8; ++r) {
      const int row = r0 + rg * 8 + r;
      if (row < n) {
        hout[row * FEAT + j] = acc[r];
        float ps = acc[r] * asv;
        float pd = acc[r] * adv;
#pragma unroll
        for (int o = 16; o >= 1; o >>= 1) {
          ps += __shfl_xor(ps, o);
          pd += __shfl_xor(pd, o);
        }
        if ((j & 31) == 0) {
          as_out[row * 4 + head] = ps;
          ad_out[row * 4 + head] = pd;
        }
      }
    }
    __syncthreads();
  }
}

// segment max of leaky_relu(as[src]+ad[dst]) over dst, 1 thread/edge
__global__ __launch_bounds__(256) void edge_max_kernel(
    const int* __restrict__ ei, const float* __restrict__ as_,
    const float* __restrict__ ad_, unsigned* __restrict__ mkey, int E, int ET) {
  int e = blockIdx.x * blockDim.x + threadIdx.x;
  if (e >= ET) return;
  int s, d;
  if (e < E) { s = ei[e]; d = ei[E + e]; } else { s = d = e - E; }
  const float4 A = *(const float4*)(as_ + s * 4);
  const float4 B = *(const float4*)(ad_ + d * 4);
  atomicMax(mkey + d * 4 + 0, flipf(lreluf(A.x + B.x)));
  atomicMax(mkey + d * 4 + 1, flipf(lreluf(A.y + B.y)));
  atomicMax(mkey + d * 4 + 2, flipf(lreluf(A.z + B.z)));
  atomicMax(mkey + d * 4 + 3, flipf(lreluf(A.w + B.w)));
}

// denom[dst] += exp(e - m[dst]), 1 thread/edge
__global__ __launch_bounds__(256) void edge_sum_kernel(
    const int* __restrict__ ei, const float* __restrict__ as_,
    const float* __restrict__ ad_, const unsigned* __restrict__ mkey,
    float* __restrict__ denom, int E, int ET) {
  int e = blockIdx.x * blockDim.x + threadIdx.x;
  if (e >= ET) return;
  int s, d;
  if (e < E) { s = ei[e]; d = ei[E + e]; } else { s = d = e - E; }
  const float4 A = *(const float4*)(as_ + s * 4);
  const float4 B = *(const float4*)(ad_ + d * 4);
#pragma unroll
  for (int h = 0; h < 4; ++h) {
    float ev = lreluf((&A.x)[h] + (&B.x)[h]);
    float m = unflipf(mkey[d * 4 + h]);
    unsafeAtomicAdd(denom + d * 4 + h, __expf(ev - m));
  }
}

// acc[dst] += h[src] * alpha(e), 32 threads/edge (4 feat each)
__global__ __launch_bounds__(256) void agg_kernel(
    const int* __restrict__ ei, const float* __restrict__ as_,
    const float* __restrict__ ad_, const unsigned* __restrict__ mkey,
    const float* __restrict__ denom, const float* __restrict__ h,
    float* __restrict__ acc, int E, int ET) {
  int tid = blockIdx.x * blockDim.x + threadIdx.x;
  int e = tid >> 5;
  if (e >= ET) return;
  int l = tid & 31;
  int s, d;
  if (e < E) { s = ei[e]; d = ei[E + e]; } else { s = d = e - E; }
  int hd = l >> 3;
  float ev = lreluf(as_[s * 4 + hd] + ad_[d * 4 + hd]);
  float m = unflipf(mkey[d * 4 + hd]);
  float w = __expf(ev - m) / (denom[d * 4 + hd] + 1e-16f);
  float4 hv = *(const float4*)(h + s * FEAT + l * 4);
  float* dst = acc + d * FEAT + l * 4;
  unsafeAtomicAdd(dst + 0, hv.x * w);
  unsafeAtomicAdd(dst + 1, hv.y * w);
  unsafeAtomicAdd(dst + 2, hv.z * w);
  unsafeAtomicAdd(dst + 3, hv.w * w);
}

// out[n,0:2] = elu(acc[n]+b) @ Wfc + bfc ; 32 lanes/node
__global__ __launch_bounds__(256) void fc_kernel(
    const float* __restrict__ acc, const float* __restrict__ bias,
    const float* __restrict__ Wfc, const float* __restrict__ bfc,
    float* __restrict__ out, int n) {
  __shared__ float wl[256];
  __shared__ float bl[128];
  const int t = threadIdx.x;
  wl[t] = Wfc[t & 255];
  if (t < 128) bl[t] = bias[t];
  __syncthreads();
  int idx = blockIdx.x * 256 + t;
  int node = idx >> 5;
  int l = idx & 5 * 0 + (idx & 31);  // l = idx & 31
  if (node >= n) return;
  float4 v = *(const float4*)(acc + node * FEAT + l * 4);
  float h0 = eluf(v.x + bl[l * 4 + 0]);
  float h1 = eluf(v.y + bl[l * 4 + 1]);
  float h2 = eluf(v.z + bl[l * 4 + 2]);
  float h3 = eluf(v.w + bl[l * 4 + 3]);
  float s0 = h0 * wl[(l * 4 + 0) * 2 + 0] + h1 * wl[(l * 4 + 1) * 2 + 0] +
             h2 * wl[(l * 4 + 2) * 2 + 0] + h3 * wl[(l * 4 + 3) * 2 + 0];
  float s1 = h0 * wl[(l * 4 + 0) * 2 + 1] + h1 * wl[(l * 4 + 1) * 2 + 1] +
             h2 * wl[(l * 4 + 2) * 2 + 1] + h3 * wl[(l * 4 + 3) * 2 + 1];
#pragma unroll
  for (int o = 16; o >= 1; o >>= 1) {
    s0 += __shfl_xor(s0, o);
    s1 += __shfl_xor(s1, o);
  }
  if (l == 0) {
    out[node * 2 + 0] = s0 + bfc[0];
    out[node * 2 + 1] = s1 + bfc[1];
  }
}

extern "C" void kernel_launch(void* const* d_in, const int* in_sizes, int n_in,
                              void* d_out, int out_size, void* d_ws, size_t ws_size,
                              hipStream_t stream) {
  const float* x   = (const float*)d_in[0];
  const int*   ei  = (const int*)d_in[1];
  const float* W1  = (const float*)d_in[2];
  const float* as1 = (const float*)d_in[3];
  const float* ad1 = (const float*)d_in[4];
  const float* b1  = (const float*)d_in[5];
  const float* W2  = (const float*)d_in[6];
  const float* as2 = (const float*)d_in[7];
  const float* ad2 = (const float*)d_in[8];
  const float* b2  = (const float*)d_in[9];
  const float* Wfc = (const float*)d_in[10];
  const float* bfc = (const float*)d_in[11];
  float* out = (float*)d_out;

  const int N = in_sizes[0] / FEAT;
  const int E = in_sizes[1] / 2;
  const int ET = E + N;

  float* ws = (float*)d_ws;
  float* hraw = ws;                            // N*128
  float* acc  = hraw + (size_t)N * FEAT;       // N*128
  float* asb  = acc + (size_t)N * FEAT;        // N*4
  float* adb  = asb + (size_t)N * 4;           // N*4
  unsigned* mkey = (unsigned*)(adb + (size_t)N * 4);  // N*4
  float* denom = (float*)(mkey + (size_t)N * 4);      // N*4

  const dim3 b256(256);
  const int zgrid = 2048;
  const int ggrid = 512;
  const int egrid = (ET + 255) / 256;
  const int agrid = (ET * 32 + 255) / 256;
  const int fgrid = (N * 32 + 255) / 256;
  const int nacc4 = N * FEAT / 4;
  const int nmd4 = N;  // N*4/4

  // ---- layer 1 ----
  zero_kernel<<<zgrid, b256, 0, stream>>>((float4*)acc, (uint4*)mkey, (float4*)denom, nacc4, nmd4);
  gemm_kernel<<<ggrid, b256, 0, stream>>>(x, W1, nullptr, as1, ad1, hraw, asb, adb, N);
  edge_max_kernel<<<egrid, b256, 0, stream>>>(ei, asb, adb, mkey, E, ET);
  edge_sum_kernel<<<egrid, b256, 0, stream>>>(ei, asb, adb, mkey, denom, E, ET);
  agg_kernel<<<agrid, b256, 0, stream>>>(ei, asb, adb, mkey, denom, hraw, acc, E, ET);

  // ---- layer 2 ---- (gemm reads acc with elu(.+b1) fused, then acc is recycled)
  gemm_kernel<<<ggrid, b256, 0, stream>>>(acc, W2, b1, as2, ad2, hraw, asb, adb, N);
  zero_kernel<<<zgrid, b256, 0, stream>>>((float4*)acc, (uint4*)mkey, (float4*)denom, nacc4, nmd4);
  edge_max_kernel<<<egrid, b256, 0, stream>>>(ei, asb, adb, mkey, E, ET);
  edge_sum_kernel<<<egrid, b256, 0, stream>>>(ei, asb, adb, mkey, denom, E, ET);
  agg_kernel<<<agrid, b256, 0, stream>>>(ei, asb, adb, mkey, denom, hraw, acc, E, ET);

  // ---- fc head ----
  fc_kernel<<<fgrid, b256, 0, stream>>>(acc, b2, Wfc, bfc, out, N);
}

// Round 2
// 781.162 us; speedup vs baseline: 9.1460x; 9.1460x over previous
//
#include <hip/hip_runtime.h>
#include <math.h>

#define FEAT 128

__device__ __forceinline__ float eluf(float x) {
  return x > 0.0f ? x : (__expf(x) - 1.0f);
}
__device__ __forceinline__ float lreluf(float x) {
  return x > 0.0f ? x : 0.2f * x;
}

// ---------------- CSR build (edge_index is shared by both layers) ----------------

__global__ __launch_bounds__(256) void zero_int_kernel(int* __restrict__ p, int n) {
  int i = blockIdx.x * 256 + threadIdx.x;
  if (i < n) p[i] = 0;
}

// count incoming edges per dst (self-loops appended: edge ids [E, E+N) are node e-E)
__global__ __launch_bounds__(256) void hist_kernel(const int* __restrict__ ei,
                                                   int* __restrict__ cnt, int E, int ET) {
  int e = blockIdx.x * 256 + threadIdx.x;
  if (e >= ET) return;
  int d = (e < E) ? ei[E + e] : (e - E);
  atomicAdd(&cnt[d], 1);
}

// block-level exclusive scan: each block covers 1024 elements (256 thr x 4)
__global__ __launch_bounds__(256) void scan1_kernel(const int* __restrict__ cnt,
                                                    int* __restrict__ pre,
                                                    int* __restrict__ bsum, int n) {
  __shared__ int sd[256];
  const int t = threadIdx.x;
  const int idx = blockIdx.x * 1024 + t * 4;
  int4 v = make_int4(0, 0, 0, 0);
  if (idx + 3 < n) {
    v = *(const int4*)(cnt + idx);
  } else {
    if (idx < n)     v.x = cnt[idx];
    if (idx + 1 < n) v.y = cnt[idx + 1];
    if (idx + 2 < n) v.z = cnt[idx + 2];
    if (idx + 3 < n) v.w = cnt[idx + 3];
  }
  const int tsum = v.x + v.y + v.z + v.w;
  sd[t] = tsum;
  __syncthreads();
  for (int o = 1; o < 256; o <<= 1) {
    int x = (t >= o) ? sd[t - o] : 0;
    __syncthreads();
    sd[t] += x;
    __syncthreads();
  }
  const int excl = sd[t] - tsum;
  if (idx < n)     pre[idx]     = excl;
  if (idx + 1 < n) pre[idx + 1] = excl + v.x;
  if (idx + 2 < n) pre[idx + 2] = excl + v.x + v.y;
  if (idx + 3 < n) pre[idx + 3] = excl + v.x + v.y + v.z;
  if (t == 255) bsum[blockIdx.x] = sd[255];
}

// exclusive scan of block sums (nb <= 256)
__global__ __launch_bounds__(256) void scan2_kernel(int* __restrict__ bsum, int nb) {
  __shared__ int sd[256];
  const int t = threadIdx.x;
  int v = (t < nb) ? bsum[t] : 0;
  sd[t] = v;
  __syncthreads();
  for (int o = 1; o < 256; o <<= 1) {
    int x = (t >= o) ? sd[t - o] : 0;
    __syncthreads();
    sd[t] += x;
    __syncthreads();
  }
  if (t < nb) bsum[t] = sd[t] - v;
}

__global__ __launch_bounds__(256) void scan3_kernel(const int* __restrict__ pre,
                                                    const int* __restrict__ bsum,
                                                    int* __restrict__ row_ptr,
                                                    int* __restrict__ cursor, int n, int ET) {
  int i = blockIdx.x * 256 + threadIdx.x;
  if (i < n) {
    int v = pre[i] + bsum[i >> 10];
    row_ptr[i] = v;
    cursor[i] = v;
  }
  if (i == 0) row_ptr[n] = ET;
}

// scatter src ids into dst-sorted order
__global__ __launch_bounds__(256) void scatter_kernel(const int* __restrict__ ei,
                                                      int* __restrict__ cursor,
                                                      int* __restrict__ esrc, int E, int ET) {
  int e = blockIdx.x * 256 + threadIdx.x;
  if (e >= ET) return;
  int s, d;
  if (e < E) { s = ei[e]; d = ei[E + e]; } else { s = d = e - E; }
  int pos = atomicAdd(&cursor[d], 1);
  esrc[pos] = s;
}

// ---------------- dense transform: h = transform(in) @ W + alpha epilogue ----------------
// transform = elu(x + tb) when tb != nullptr (folds previous layer's bias+ELU).
__global__ __launch_bounds__(256, 2) void gemm_kernel(
    const float* __restrict__ in, const float* __restrict__ W,
    const float* __restrict__ tb,
    const float* __restrict__ avs, const float* __restrict__ avd,
    float* __restrict__ hout, float* __restrict__ as_out, float* __restrict__ ad_out,
    int n) {
  __shared__ float Wl[128 * 128];
  __shared__ float xl[16][128];
  __shared__ float asl[128];
  __shared__ float adl[128];
  const int t = threadIdx.x;

  for (int c = 0; c < 16; ++c) {
    int id = c * 256 + t;
    *(float4*)&Wl[id * 4] = *(const float4*)&W[id * 4];
  }
  if (t < 128) { asl[t] = avs[t]; adl[t] = avd[t]; }
  __syncthreads();

  const int j = t & 127;
  const int rg = t >> 7;
  const float asv = asl[j];
  const float adv = adl[j];
  const int head = j >> 5;
  const int ntiles = (n + 15) >> 4;

  for (int tile = blockIdx.x; tile < ntiles; tile += gridDim.x) {
    const int r0 = tile << 4;
    for (int c = 0; c < 2; ++c) {
      int id = c * 256 + t;
      int r = id >> 5;
      int k4 = (id & 31) * 4;
      int row = r0 + r;
      float4 v = make_float4(0.f, 0.f, 0.f, 0.f);
      if (row < n) {
        v = *(const float4*)&in[row * FEAT + k4];
        if (tb) {
          v.x = eluf(v.x + tb[k4 + 0]);
          v.y = eluf(v.y + tb[k4 + 1]);
          v.z = eluf(v.z + tb[k4 + 2]);
          v.w = eluf(v.w + tb[k4 + 3]);
        }
      }
      *(float4*)&xl[r][k4] = v;
    }
    __syncthreads();

    float acc[8];
#pragma unroll
    for (int r = 0; r < 8; ++r) acc[r] = 0.f;

    for (int k4 = 0; k4 < 128; k4 += 4) {
      const float w0 = Wl[(k4 + 0) * 128 + j];
      const float w1 = Wl[(k4 + 1) * 128 + j];
      const float w2 = Wl[(k4 + 2) * 128 + j];
      const float w3 = Wl[(k4 + 3) * 128 + j];
#pragma unroll
      for (int r = 0; r < 8; ++r) {
        float4 xv = *(const float4*)&xl[rg * 8 + r][k4];
        acc[r] = fmaf(xv.x, w0, acc[r]);
        acc[r] = fmaf(xv.y, w1, acc[r]);
        acc[r] = fmaf(xv.z, w2, acc[r]);
        acc[r] = fmaf(xv.w, w3, acc[r]);
      }
    }

#pragma unroll
    for (int r = 0; r < 8; ++r) {
      const int row = r0 + rg * 8 + r;
      if (row < n) {
        hout[row * FEAT + j] = acc[r];
        float ps = acc[r] * asv;
        float pd = acc[r] * adv;
#pragma unroll
        for (int o = 16; o >= 1; o >>= 1) {
          ps += __shfl_xor(ps, o);
          pd += __shfl_xor(pd, o);
        }
        if ((j & 31) == 0) {
          as_out[row * 4 + head] = ps;
          ad_out[row * 4 + head] = pd;
        }
      }
    }
    __syncthreads();
  }
}

// ---------------- per-node softmax + aggregation (atomic-free) ----------------
// One 64-lane wave per node. Lane l owns features [2l, 2l+1], head = l>>4.
__global__ __launch_bounds__(256) void node_gat_kernel(
    const int* __restrict__ row_ptr, const int* __restrict__ esrc,
    const float* __restrict__ as_, const float* __restrict__ ad_,
    const float* __restrict__ h, float* __restrict__ acc, int n) {
  const int wid = (blockIdx.x * 256 + threadIdx.x) >> 6;  // node id
  if (wid >= n) return;
  const int l = threadIdx.x & 63;
  const int begin = row_ptr[wid];
  const int end = row_ptr[wid + 1];

  // ---- pass 1: per-head max over incoming edges (16 edges x 4 heads per iter)
  const int hd4 = l & 3;
  const float adv4 = ad_[wid * 4 + hd4];
  float m = -1e30f;
  for (int base = begin; base < end; base += 16) {
    const int eidx = base + (l >> 2);
    if (eidx < end) {
      const int s = esrc[eidx];
      m = fmaxf(m, lreluf(as_[s * 4 + hd4] + adv4));
    }
  }
#pragma unroll
  for (int o = 4; o < 64; o <<= 1) m = fmaxf(m, __shfl_xor(m, o));
  // lane k (k<4) now holds max of head k; redistribute to this lane's head
  const int hd = l >> 4;
  const float mh = __shfl(m, hd);
  const float adv = ad_[wid * 4 + hd];

  // ---- pass 2: weighted aggregation, 2-edge unroll for MLP
  float2 a2 = make_float2(0.f, 0.f);
  float den = 0.f;  // identical across the 16 lanes of a head group
  int eidx = begin;
  for (; eidx + 1 < end; eidx += 2) {
    const int s0 = esrc[eidx];
    const int s1 = esrc[eidx + 1];
    const float w0 = __expf(lreluf(as_[s0 * 4 + hd] + adv) - mh);
    const float w1 = __expf(lreluf(as_[s1 * 4 + hd] + adv) - mh);
    const float2 h0 = *(const float2*)(h + (size_t)s0 * FEAT + l * 2);
    const float2 h1 = *(const float2*)(h + (size_t)s1 * FEAT + l * 2);
    den += w0 + w1;
    a2.x = fmaf(h0.x, w0, fmaf(h1.x, w1, a2.x));
    a2.y = fmaf(h0.y, w0, fmaf(h1.y, w1, a2.y));
  }
  if (eidx < end) {
    const int s0 = esrc[eidx];
    const float w0 = __expf(lreluf(as_[s0 * 4 + hd] + adv) - mh);
    const float2 h0 = *(const float2*)(h + (size_t)s0 * FEAT + l * 2);
    den += w0;
    a2.x = fmaf(h0.x, w0, a2.x);
    a2.y = fmaf(h0.y, w0, a2.y);
  }
  const float inv = 1.0f / (den + 1e-16f);
  acc[wid * FEAT + l * 2 + 0] = a2.x * inv;
  acc[wid * FEAT + l * 2 + 1] = a2.y * inv;
}

// ---------------- FC head: out = elu(acc+b) @ Wfc + bfc ----------------
__global__ __launch_bounds__(256) void fc_kernel(
    const float* __restrict__ acc, const float* __restrict__ bias,
    const float* __restrict__ Wfc, const float* __restrict__ bfc,
    float* __restrict__ out, int n) {
  __shared__ float wl[256];
  __shared__ float bl[128];
  const int t = threadIdx.x;
  wl[t] = Wfc[t & 255];
  if (t < 128) bl[t] = bias[t];
  __syncthreads();
  int idx = blockIdx.x * 256 + t;
  int node = idx >> 5;
  int l = idx & 31;
  if (node >= n) return;
  float4 v = *(const float4*)(acc + node * FEAT + l * 4);
  float h0 = eluf(v.x + bl[l * 4 + 0]);
  float h1 = eluf(v.y + bl[l * 4 + 1]);
  float h2 = eluf(v.z + bl[l * 4 + 2]);
  float h3 = eluf(v.w + bl[l * 4 + 3]);
  float s0 = h0 * wl[(l * 4 + 0) * 2 + 0] + h1 * wl[(l * 4 + 1) * 2 + 0] +
             h2 * wl[(l * 4 + 2) * 2 + 0] + h3 * wl[(l * 4 + 3) * 2 + 0];
  float s1 = h0 * wl[(l * 4 + 0) * 2 + 1] + h1 * wl[(l * 4 + 1) * 2 + 1] +
             h2 * wl[(l * 4 + 2) * 2 + 1] + h3 * wl[(l * 4 + 3) * 2 + 1];
#pragma unroll
  for (int o = 16; o >= 1; o >>= 1) {
    s0 += __shfl_xor(s0, o);
    s1 += __shfl_xor(s1, o);
  }
  if (l == 0) {
    out[node * 2 + 0] = s0 + bfc[0];
    out[node * 2 + 1] = s1 + bfc[1];
  }
}

extern "C" void kernel_launch(void* const* d_in, const int* in_sizes, int n_in,
                              void* d_out, int out_size, void* d_ws, size_t ws_size,
                              hipStream_t stream) {
  const float* x   = (const float*)d_in[0];
  const int*   ei  = (const int*)d_in[1];
  const float* W1  = (const float*)d_in[2];
  const float* as1 = (const float*)d_in[3];
  const float* ad1 = (const float*)d_in[4];
  const float* b1  = (const float*)d_in[5];
  const float* W2  = (const float*)d_in[6];
  const float* as2 = (const float*)d_in[7];
  const float* ad2 = (const float*)d_in[8];
  const float* b2  = (const float*)d_in[9];
  const float* Wfc = (const float*)d_in[10];
  const float* bfc = (const float*)d_in[11];
  float* out = (float*)d_out;

  const int N = in_sizes[0] / FEAT;
  const int E = in_sizes[1] / 2;
  const int ET = E + N;

  // workspace layout
  float* ws = (float*)d_ws;
  float* hraw = ws;                              // N*128 f32
  float* acc  = hraw + (size_t)N * FEAT;         // N*128 f32
  float* asb  = acc + (size_t)N * FEAT;          // N*4
  float* adb  = asb + (size_t)N * 4;             // N*4
  int* cnt     = (int*)(adb + (size_t)N * 4);    // N
  int* pre     = cnt + N;                        // N
  int* bsum    = pre + N;                        // 256
  int* row_ptr = bsum + 256;                     // N+1
  int* cursor  = row_ptr + (N + 1);              // N
  int* esrc    = cursor + N;                     // ET

  const dim3 b256(256);
  const int egrid = (ET + 255) / 256;
  const int ngrid = (N + 255) / 256;
  const int nb = (N + 1023) / 1024;

  // ---- CSR build (edge structure shared by both layers) ----
  zero_int_kernel<<<ngrid, b256, 0, stream>>>(cnt, N);
  hist_kernel<<<egrid, b256, 0, stream>>>(ei, cnt, E, ET);
  scan1_kernel<<<nb, b256, 0, stream>>>(cnt, pre, bsum, N);
  scan2_kernel<<<1, b256, 0, stream>>>(bsum, nb);
  scan3_kernel<<<ngrid, b256, 0, stream>>>(pre, bsum, row_ptr, cursor, N, ET);
  scatter_kernel<<<egrid, b256, 0, stream>>>(ei, cursor, esrc, E, ET);

  const int ggrid = 512;
  const int wgrid = (N * 64 + 255) / 256;  // one wave per node
  const int fgrid = (N * 32 + 255) / 256;

  // ---- layer 1 ----
  gemm_kernel<<<ggrid, b256, 0, stream>>>(x, W1, nullptr, as1, ad1, hraw, asb, adb, N);
  node_gat_kernel<<<wgrid, b256, 0, stream>>>(row_ptr, esrc, asb, adb, hraw, acc, N);

  // ---- layer 2 ----
  gemm_kernel<<<ggrid, b256, 0, stream>>>(acc, W2, b1, as2, ad2, hraw, asb, adb, N);
  node_gat_kernel<<<wgrid, b256, 0, stream>>>(row_ptr, esrc, asb, adb, hraw, acc, N);

  // ---- fc head ----
  fc_kernel<<<fgrid, b256, 0, stream>>>(acc, b2, Wfc, bfc, out, N);
}

// Round 3
// 627.065 us; speedup vs baseline: 11.3936x; 1.2457x over previous
//
#include <hip/hip_runtime.h>
#include <hip/hip_fp16.h>
#include <math.h>

#define FEAT 128

__device__ __forceinline__ float eluf(float x) {
  return x > 0.0f ? x : (__expf(x) - 1.0f);
}
__device__ __forceinline__ float lreluf(float x) {
  return x > 0.0f ? x : 0.2f * x;
}

// ---------------- CSR build (edge_index is shared by both layers) ----------------

__global__ __launch_bounds__(256) void zero_int_kernel(int* __restrict__ p, int n) {
  int i = blockIdx.x * 256 + threadIdx.x;
  if (i < n) p[i] = 0;
}

// count incoming edges per dst (self-loops appended: edge ids [E, E+N) are node e-E)
__global__ __launch_bounds__(256) void hist_kernel(const int* __restrict__ ei,
                                                   int* __restrict__ cnt, int E, int ET) {
  int e = blockIdx.x * 256 + threadIdx.x;
  if (e >= ET) return;
  int d = (e < E) ? ei[E + e] : (e - E);
  atomicAdd(&cnt[d], 1);
}

// block-level exclusive scan: each block covers 1024 elements (256 thr x 4)
__global__ __launch_bounds__(256) void scan1_kernel(const int* __restrict__ cnt,
                                                    int* __restrict__ pre,
                                                    int* __restrict__ bsum, int n) {
  __shared__ int sd[256];
  const int t = threadIdx.x;
  const int idx = blockIdx.x * 1024 + t * 4;
  int4 v = make_int4(0, 0, 0, 0);
  if (idx + 3 < n) {
    v = *(const int4*)(cnt + idx);
  } else {
    if (idx < n)     v.x = cnt[idx];
    if (idx + 1 < n) v.y = cnt[idx + 1];
    if (idx + 2 < n) v.z = cnt[idx + 2];
    if (idx + 3 < n) v.w = cnt[idx + 3];
  }
  const int tsum = v.x + v.y + v.z + v.w;
  sd[t] = tsum;
  __syncthreads();
  for (int o = 1; o < 256; o <<= 1) {
    int x = (t >= o) ? sd[t - o] : 0;
    __syncthreads();
    sd[t] += x;
    __syncthreads();
  }
  const int excl = sd[t] - tsum;
  if (idx < n)     pre[idx]     = excl;
  if (idx + 1 < n) pre[idx + 1] = excl + v.x;
  if (idx + 2 < n) pre[idx + 2] = excl + v.x + v.y;
  if (idx + 3 < n) pre[idx + 3] = excl + v.x + v.y + v.z;
  if (t == 255) bsum[blockIdx.x] = sd[255];
}

// exclusive scan of block sums (nb <= 256)
__global__ __launch_bounds__(256) void scan2_kernel(int* __restrict__ bsum, int nb) {
  __shared__ int sd[256];
  const int t = threadIdx.x;
  int v = (t < nb) ? bsum[t] : 0;
  sd[t] = v;
  __syncthreads();
  for (int o = 1; o < 256; o <<= 1) {
    int x = (t >= o) ? sd[t - o] : 0;
    __syncthreads();
    sd[t] += x;
    __syncthreads();
  }
  if (t < nb) bsum[t] = sd[t] - v;
}

__global__ __launch_bounds__(256) void scan3_kernel(const int* __restrict__ pre,
                                                    const int* __restrict__ bsum,
                                                    int* __restrict__ row_ptr,
                                                    int* __restrict__ cursor, int n, int ET) {
  int i = blockIdx.x * 256 + threadIdx.x;
  if (i < n) {
    int v = pre[i] + bsum[i >> 10];
    row_ptr[i] = v;
    cursor[i] = v;
  }
  if (i == 0) row_ptr[n] = ET;
}

// scatter src ids into dst-sorted order
__global__ __launch_bounds__(256) void scatter_kernel(const int* __restrict__ ei,
                                                      int* __restrict__ cursor,
                                                      int* __restrict__ esrc, int E, int ET) {
  int e = blockIdx.x * 256 + threadIdx.x;
  if (e >= ET) return;
  int s, d;
  if (e < E) { s = ei[e]; d = ei[E + e]; } else { s = d = e - E; }
  int pos = atomicAdd(&cursor[d], 1);
  esrc[pos] = s;
}

// ---------------- dense transform: h = transform(in) @ W + alpha epilogue ----------------
// transform = elu(x + tb) when tb != nullptr (folds previous layer's bias+ELU).
// hout is written as fp16 (gather bandwidth in node_gat_kernel is the bottleneck).
__global__ __launch_bounds__(256, 2) void gemm_kernel(
    const float* __restrict__ in, const float* __restrict__ W,
    const float* __restrict__ tb,
    const float* __restrict__ avs, const float* __restrict__ avd,
    __half* __restrict__ hout, float* __restrict__ as_out, float* __restrict__ ad_out,
    int n) {
  __shared__ float Wl[128 * 128];
  __shared__ float xl[16][128];
  __shared__ float asl[128];
  __shared__ float adl[128];
  const int t = threadIdx.x;

  for (int c = 0; c < 16; ++c) {
    int id = c * 256 + t;
    *(float4*)&Wl[id * 4] = *(const float4*)&W[id * 4];
  }
  if (t < 128) { asl[t] = avs[t]; adl[t] = avd[t]; }
  __syncthreads();

  const int j = t & 127;
  const int rg = t >> 7;
  const float asv = asl[j];
  const float adv = adl[j];
  const int head = j >> 5;
  const int ntiles = (n + 15) >> 4;

  for (int tile = blockIdx.x; tile < ntiles; tile += gridDim.x) {
    const int r0 = tile << 4;
    for (int c = 0; c < 2; ++c) {
      int id = c * 256 + t;
      int r = id >> 5;
      int k4 = (id & 31) * 4;
      int row = r0 + r;
      float4 v = make_float4(0.f, 0.f, 0.f, 0.f);
      if (row < n) {
        v = *(const float4*)&in[row * FEAT + k4];
        if (tb) {
          v.x = eluf(v.x + tb[k4 + 0]);
          v.y = eluf(v.y + tb[k4 + 1]);
          v.z = eluf(v.z + tb[k4 + 2]);
          v.w = eluf(v.w + tb[k4 + 3]);
        }
      }
      *(float4*)&xl[r][k4] = v;
    }
    __syncthreads();

    float acc[8];
#pragma unroll
    for (int r = 0; r < 8; ++r) acc[r] = 0.f;

    for (int k4 = 0; k4 < 128; k4 += 4) {
      const float w0 = Wl[(k4 + 0) * 128 + j];
      const float w1 = Wl[(k4 + 1) * 128 + j];
      const float w2 = Wl[(k4 + 2) * 128 + j];
      const float w3 = Wl[(k4 + 3) * 128 + j];
#pragma unroll
      for (int r = 0; r < 8; ++r) {
        float4 xv = *(const float4*)&xl[rg * 8 + r][k4];
        acc[r] = fmaf(xv.x, w0, acc[r]);
        acc[r] = fmaf(xv.y, w1, acc[r]);
        acc[r] = fmaf(xv.z, w2, acc[r]);
        acc[r] = fmaf(xv.w, w3, acc[r]);
      }
    }

#pragma unroll
    for (int r = 0; r < 8; ++r) {
      const int row = r0 + rg * 8 + r;
      if (row < n) {
        hout[(size_t)row * FEAT + j] = __float2half(acc[r]);
        float ps = acc[r] * asv;
        float pd = acc[r] * adv;
#pragma unroll
        for (int o = 16; o >= 1; o >>= 1) {
          ps += __shfl_xor(ps, o);
          pd += __shfl_xor(pd, o);
        }
        if ((j & 31) == 0) {
          as_out[row * 4 + head] = ps;
          ad_out[row * 4 + head] = pd;
        }
      }
    }
    __syncthreads();
  }
}

// ---------------- per-node softmax + aggregation (atomic-free, no max pass) ----------------
// One 64-lane wave per node. Lane l owns features [2l, 2l+1] (one __half2), head = l>>4.
// Softmax without max subtraction: e = lrelu(as+ad) is bounded (|e| ~ a few), exp is safe
// in f32 and alpha = exp(e)/sum exp(e) is mathematically identical to the ref.
__global__ __launch_bounds__(256) void node_gat_kernel(
    const int* __restrict__ row_ptr, const int* __restrict__ esrc,
    const float* __restrict__ as_, const float* __restrict__ ad_,
    const __half2* __restrict__ h, float* __restrict__ acc, int n) {
  const int wid = (blockIdx.x * 256 + threadIdx.x) >> 6;  // node id
  if (wid >= n) return;
  const int l = threadIdx.x & 63;
  const int begin = row_ptr[wid];
  const int end = row_ptr[wid + 1];
  const int hd = l >> 4;
  const float adv = ad_[wid * 4 + hd];

  float2 a2 = make_float2(0.f, 0.f);
  float den = 0.f;  // identical across the 16 lanes of a head group
  int e = begin;
  for (; e + 3 < end; e += 4) {
    const int s0 = esrc[e + 0];
    const int s1 = esrc[e + 1];
    const int s2 = esrc[e + 2];
    const int s3 = esrc[e + 3];
    const float w0 = __expf(lreluf(as_[s0 * 4 + hd] + adv));
    const float w1 = __expf(lreluf(as_[s1 * 4 + hd] + adv));
    const float w2 = __expf(lreluf(as_[s2 * 4 + hd] + adv));
    const float w3 = __expf(lreluf(as_[s3 * 4 + hd] + adv));
    const float2 h0 = __half22float2(h[(size_t)s0 * 64 + l]);
    const float2 h1 = __half22float2(h[(size_t)s1 * 64 + l]);
    const float2 h2 = __half22float2(h[(size_t)s2 * 64 + l]);
    const float2 h3 = __half22float2(h[(size_t)s3 * 64 + l]);
    den += (w0 + w1) + (w2 + w3);
    a2.x = fmaf(h0.x, w0, a2.x);
    a2.y = fmaf(h0.y, w0, a2.y);
    a2.x = fmaf(h1.x, w1, a2.x);
    a2.y = fmaf(h1.y, w1, a2.y);
    a2.x = fmaf(h2.x, w2, a2.x);
    a2.y = fmaf(h2.y, w2, a2.y);
    a2.x = fmaf(h3.x, w3, a2.x);
    a2.y = fmaf(h3.y, w3, a2.y);
  }
  for (; e < end; ++e) {
    const int s0 = esrc[e];
    const float w0 = __expf(lreluf(as_[s0 * 4 + hd] + adv));
    const float2 h0 = __half22float2(h[(size_t)s0 * 64 + l]);
    den += w0;
    a2.x = fmaf(h0.x, w0, a2.x);
    a2.y = fmaf(h0.y, w0, a2.y);
  }
  const float inv = 1.0f / (den + 1e-16f);
  acc[wid * FEAT + l * 2 + 0] = a2.x * inv;
  acc[wid * FEAT + l * 2 + 1] = a2.y * inv;
}

// ---------------- FC head: out = elu(acc+b) @ Wfc + bfc ----------------
__global__ __launch_bounds__(256) void fc_kernel(
    const float* __restrict__ acc, const float* __restrict__ bias,
    const float* __restrict__ Wfc, const float* __restrict__ bfc,
    float* __restrict__ out, int n) {
  __shared__ float wl[256];
  __shared__ float bl[128];
  const int t = threadIdx.x;
  wl[t] = Wfc[t & 255];
  if (t < 128) bl[t] = bias[t];
  __syncthreads();
  int idx = blockIdx.x * 256 + t;
  int node = idx >> 5;
  int l = idx & 31;
  if (node >= n) return;
  float4 v = *(const float4*)(acc + node * FEAT + l * 4);
  float h0 = eluf(v.x + bl[l * 4 + 0]);
  float h1 = eluf(v.y + bl[l * 4 + 1]);
  float h2 = eluf(v.z + bl[l * 4 + 2]);
  float h3 = eluf(v.w + bl[l * 4 + 3]);
  float s0 = h0 * wl[(l * 4 + 0) * 2 + 0] + h1 * wl[(l * 4 + 1) * 2 + 0] +
             h2 * wl[(l * 4 + 2) * 2 + 0] + h3 * wl[(l * 4 + 3) * 2 + 0];
  float s1 = h0 * wl[(l * 4 + 0) * 2 + 1] + h1 * wl[(l * 4 + 1) * 2 + 1] +
             h2 * wl[(l * 4 + 2) * 2 + 1] + h3 * wl[(l * 4 + 3) * 2 + 1];
#pragma unroll
  for (int o = 16; o >= 1; o >>= 1) {
    s0 += __shfl_xor(s0, o);
    s1 += __shfl_xor(s1, o);
  }
  if (l == 0) {
    out[node * 2 + 0] = s0 + bfc[0];
    out[node * 2 + 1] = s1 + bfc[1];
  }
}

extern "C" void kernel_launch(void* const* d_in, const int* in_sizes, int n_in,
                              void* d_out, int out_size, void* d_ws, size_t ws_size,
                              hipStream_t stream) {
  const float* x   = (const float*)d_in[0];
  const int*   ei  = (const int*)d_in[1];
  const float* W1  = (const float*)d_in[2];
  const float* as1 = (const float*)d_in[3];
  const float* ad1 = (const float*)d_in[4];
  const float* b1  = (const float*)d_in[5];
  const float* W2  = (const float*)d_in[6];
  const float* as2 = (const float*)d_in[7];
  const float* ad2 = (const float*)d_in[8];
  const float* b2  = (const float*)d_in[9];
  const float* Wfc = (const float*)d_in[10];
  const float* bfc = (const float*)d_in[11];
  float* out = (float*)d_out;

  const int N = in_sizes[0] / FEAT;
  const int E = in_sizes[1] / 2;
  const int ET = E + N;

  // workspace layout (hraw slot kept f32-sized; only half of it used now that h is fp16)
  float* ws = (float*)d_ws;
  __half* hraw = (__half*)ws;                    // N*128 fp16 (slot sized N*128 f32)
  float* acc  = ws + (size_t)N * FEAT;           // N*128 f32
  float* asb  = acc + (size_t)N * FEAT;          // N*4
  float* adb  = asb + (size_t)N * 4;             // N*4
  int* cnt     = (int*)(adb + (size_t)N * 4);    // N
  int* pre     = cnt + N;                        // N
  int* bsum    = pre + N;                        // 256
  int* row_ptr = bsum + 256;                     // N+1
  int* cursor  = row_ptr + (N + 1);              // N
  int* esrc    = cursor + N;                     // ET

  const dim3 b256(256);
  const int egrid = (ET + 255) / 256;
  const int ngrid = (N + 255) / 256;
  const int nb = (N + 1023) / 1024;

  // ---- CSR build (edge structure shared by both layers) ----
  zero_int_kernel<<<ngrid, b256, 0, stream>>>(cnt, N);
  hist_kernel<<<egrid, b256, 0, stream>>>(ei, cnt, E, ET);
  scan1_kernel<<<nb, b256, 0, stream>>>(cnt, pre, bsum, N);
  scan2_kernel<<<1, b256, 0, stream>>>(bsum, nb);
  scan3_kernel<<<ngrid, b256, 0, stream>>>(pre, bsum, row_ptr, cursor, N, ET);
  scatter_kernel<<<egrid, b256, 0, stream>>>(ei, cursor, esrc, E, ET);

  const int ggrid = 512;
  const int wgrid = (N * 64 + 255) / 256;  // one wave per node
  const int fgrid = (N * 32 + 255) / 256;

  // ---- layer 1 ----
  gemm_kernel<<<ggrid, b256, 0, stream>>>(x, W1, nullptr, as1, ad1, hraw, asb, adb, N);
  node_gat_kernel<<<wgrid, b256, 0, stream>>>(row_ptr, esrc, asb, adb, (const __half2*)hraw, acc, N);

  // ---- layer 2 ----
  gemm_kernel<<<ggrid, b256, 0, stream>>>(acc, W2, b1, as2, ad2, hraw, asb, adb, N);
  node_gat_kernel<<<wgrid, b256, 0, stream>>>(row_ptr, esrc, asb, adb, (const __half2*)hraw, acc, N);

  // ---- fc head ----
  fc_kernel<<<fgrid, b256, 0, stream>>>(acc, b2, Wfc, bfc, out, N);
}

// Round 4
// 451.803 us; speedup vs baseline: 15.8133x; 1.3879x over previous
//
#include <hip/hip_runtime.h>
#include <hip/hip_fp16.h>
#include <math.h>

#define FEAT 128

typedef _Float16 f16x8 __attribute__((ext_vector_type(8)));
typedef float f32x4 __attribute__((ext_vector_type(4)));

__device__ __forceinline__ float eluf(float x) {
  return x > 0.0f ? x : (__expf(x) - 1.0f);
}
__device__ __forceinline__ float lreluf(float x) {
  return x > 0.0f ? x : 0.2f * x;
}

// ---------------- CSR build ----------------

__global__ __launch_bounds__(256) void zero_int_kernel(int* __restrict__ p, int n) {
  int i = blockIdx.x * 256 + threadIdx.x;
  if (i < n) p[i] = 0;
}

__global__ __launch_bounds__(256) void hist_kernel(const int* __restrict__ ei,
                                                   int* __restrict__ cnt, int E, int ET) {
  int e = blockIdx.x * 256 + threadIdx.x;
  if (e >= ET) return;
  int d = (e < E) ? ei[E + e] : (e - E);
  atomicAdd(&cnt[d], 1);
}

__global__ __launch_bounds__(256) void scan1_kernel(const int* __restrict__ cnt,
                                                    int* __restrict__ pre,
                                                    int* __restrict__ bsum, int n) {
  __shared__ int sd[256];
  const int t = threadIdx.x;
  const int idx = blockIdx.x * 1024 + t * 4;
  int4 v = make_int4(0, 0, 0, 0);
  if (idx + 3 < n) {
    v = *(const int4*)(cnt + idx);
  } else {
    if (idx < n)     v.x = cnt[idx];
    if (idx + 1 < n) v.y = cnt[idx + 1];
    if (idx + 2 < n) v.z = cnt[idx + 2];
    if (idx + 3 < n) v.w = cnt[idx + 3];
  }
  const int tsum = v.x + v.y + v.z + v.w;
  sd[t] = tsum;
  __syncthreads();
  for (int o = 1; o < 256; o <<= 1) {
    int x = (t >= o) ? sd[t - o] : 0;
    __syncthreads();
    sd[t] += x;
    __syncthreads();
  }
  const int excl = sd[t] - tsum;
  if (idx < n)     pre[idx]     = excl;
  if (idx + 1 < n) pre[idx + 1] = excl + v.x;
  if (idx + 2 < n) pre[idx + 2] = excl + v.x + v.y;
  if (idx + 3 < n) pre[idx + 3] = excl + v.x + v.y + v.z;
  if (t == 255) bsum[blockIdx.x] = sd[255];
}

__global__ __launch_bounds__(256) void scan2_kernel(int* __restrict__ bsum, int nb) {
  __shared__ int sd[256];
  const int t = threadIdx.x;
  int v = (t < nb) ? bsum[t] : 0;
  sd[t] = v;
  __syncthreads();
  for (int o = 1; o < 256; o <<= 1) {
    int x = (t >= o) ? sd[t - o] : 0;
    __syncthreads();
    sd[t] += x;
    __syncthreads();
  }
  if (t < nb) bsum[t] = sd[t] - v;
}

__global__ __launch_bounds__(256) void scan3_kernel(const int* __restrict__ pre,
                                                    const int* __restrict__ bsum,
                                                    int* __restrict__ row_ptr,
                                                    int* __restrict__ cursor, int n, int ET) {
  int i = blockIdx.x * 256 + threadIdx.x;
  if (i < n) {
    int v = pre[i] + bsum[i >> 10];
    row_ptr[i] = v;
    cursor[i] = v;
  }
  if (i == 0) row_ptr[n] = ET;
}

__global__ __launch_bounds__(256) void scatter_kernel(const int* __restrict__ ei,
                                                      int* __restrict__ cursor,
                                                      int* __restrict__ esrc, int E, int ET) {
  int e = blockIdx.x * 256 + threadIdx.x;
  if (e >= ET) return;
  int s, d;
  if (e < E) { s = ei[e]; d = ei[E + e]; } else { s = d = e - E; }
  int pos = atomicAdd(&cursor[d], 1);
  esrc[pos] = s;
}

// ---------------- W fragment prepack ----------------
// frag layout: [kstep(4)][tile(9)][lane(64)][elem(8)] fp16.
// tile t covers cols 16t+0..15 of B' = [W | W@a_src^T | W@a_dst^T | 0-pad] (128+4+4+8 cols).
// lane (hi=lane>>4, li=lane&15): col = 16t+li, k = ks*32 + hi*8 + i.
// Same (hi,i)->k bijection is used for the A/x fragment in the GEMM, so the MFMA's
// internal k ordering cancels (sum over k is permutation-invariant).
__global__ __launch_bounds__(256) void pack_w_kernel(
    const float* __restrict__ W, const float* __restrict__ a_src,
    const float* __restrict__ a_dst, __half* __restrict__ frag) {
  int tid = blockIdx.x * 256 + threadIdx.x;
  if (tid >= 4 * 9 * 64) return;
  int lane = tid & 63;
  int tile = (tid >> 6) % 9;
  int ks = tid / (9 * 64);
  int li = lane & 15, hi = lane >> 4;
  int col = tile * 16 + li;
  __half* dst = frag + (size_t)tid * 8;
  for (int i = 0; i < 8; ++i) {
    int k = ks * 32 + hi * 8 + i;
    float v = 0.f;
    if (col < 128) {
      v = W[k * 128 + col];
    } else if (col < 132) {
      int h = col - 128;
      float s = 0.f;
      for (int j = 0; j < 32; ++j) s += W[k * 128 + h * 32 + j] * a_src[h * 32 + j];
      v = s;
    } else if (col < 136) {
      int h = col - 132;
      float s = 0.f;
      for (int j = 0; j < 32; ++j) s += W[k * 128 + h * 32 + j] * a_dst[h * 32 + j];
      v = s;
    }
    dst[i] = __float2half(v);
  }
}

// ---------------- MFMA GEMM: h = in @ W (+ fused alpha columns) ----------------
// One wave per 16-row tile; zero LDS. A-operand = W-fragments (m = col of W),
// B-operand = x rows (n = row index). D: n = lane&15 (row), m = (lane>>4)*4+reg (col).
template <bool F32IN>
__global__ __launch_bounds__(256) void gemm_mfma_kernel(
    const void* __restrict__ in, const __half* __restrict__ frag,
    __half* __restrict__ hout, float* __restrict__ as_out, float* __restrict__ ad_out,
    int nrows) {
  const int wid = (blockIdx.x * 256 + threadIdx.x) >> 6;
  const int lane = threadIdx.x & 63;
  const int li = lane & 15, hi = lane >> 4;
  int row = wid * 16 + li;
  const bool valid = row < nrows;
  if (wid * 16 >= nrows) return;
  if (!valid) row = nrows - 1;  // safe load, stores predicated

  const f16x8* fragv = (const f16x8*)frag;

  f32x4 acc[9];
#pragma unroll
  for (int t = 0; t < 9; ++t) acc[t] = (f32x4){0.f, 0.f, 0.f, 0.f};

#pragma unroll
  for (int ks = 0; ks < 4; ++ks) {
    f16x8 xf;
    if (F32IN) {
      const float* xp = (const float*)in + (size_t)row * FEAT + ks * 32 + hi * 8;
      float4 v0 = *(const float4*)xp;
      float4 v1 = *(const float4*)(xp + 4);
      xf[0] = (_Float16)v0.x; xf[1] = (_Float16)v0.y;
      xf[2] = (_Float16)v0.z; xf[3] = (_Float16)v0.w;
      xf[4] = (_Float16)v1.x; xf[5] = (_Float16)v1.y;
      xf[6] = (_Float16)v1.z; xf[7] = (_Float16)v1.w;
    } else {
      xf = *(const f16x8*)((const __half*)in + (size_t)row * FEAT + ks * 32 + hi * 8);
    }
#pragma unroll
    for (int t = 0; t < 9; ++t) {
      f16x8 wf = fragv[(ks * 9 + t) * 64 + lane];
      acc[t] = __builtin_amdgcn_mfma_f32_16x16x32_f16(wf, xf, acc[t], 0, 0, 0);
    }
  }

  if (!valid) return;
  // h columns: lane holds cols 16t + hi*4 + {0..3} of its row
#pragma unroll
  for (int t = 0; t < 8; ++t) {
    union { __half2 h[2]; uint2 u; } pk;
    pk.h[0] = __floats2half2_rn(acc[t][0], acc[t][1]);
    pk.h[1] = __floats2half2_rn(acc[t][2], acc[t][3]);
    *(uint2*)(hout + (size_t)row * FEAT + t * 16 + hi * 4) = pk.u;
  }
  // alpha columns (tile 8): hi==0 -> as[0..3], hi==1 -> ad[0..3]
  if (hi == 0) *(float4*)(as_out + row * 4) = make_float4(acc[8][0], acc[8][1], acc[8][2], acc[8][3]);
  if (hi == 1) *(float4*)(ad_out + row * 4) = make_float4(acc[8][0], acc[8][1], acc[8][2], acc[8][3]);
}

// ---------------- per-node softmax + aggregation ----------------
// One wave per node; lane l owns features [2l,2l+1]; head = l>>4.
// out16 != null: write fp16 elu(agg + bias) (next GEMM's input).
// else: write f32 agg to outf (consumed by fc_kernel).
__global__ __launch_bounds__(256) void node_gat_kernel(
    const int* __restrict__ row_ptr, const int* __restrict__ esrc,
    const float* __restrict__ as_, const float* __restrict__ ad_,
    const __half2* __restrict__ h, const float* __restrict__ bias,
    __half2* __restrict__ out16, float* __restrict__ outf, int n) {
  const int wid = (blockIdx.x * 256 + threadIdx.x) >> 6;
  if (wid >= n) return;
  const int l = threadIdx.x & 63;
  const int begin = row_ptr[wid];
  const int end = row_ptr[wid + 1];
  const int hd = l >> 4;
  const float adv = ad_[wid * 4 + hd];

  float2 a2 = make_float2(0.f, 0.f);
  float den = 0.f;
  int e = begin;
  for (; e + 3 < end; e += 4) {
    const int s0 = esrc[e + 0];
    const int s1 = esrc[e + 1];
    const int s2 = esrc[e + 2];
    const int s3 = esrc[e + 3];
    const float w0 = __expf(lreluf(as_[s0 * 4 + hd] + adv));
    const float w1 = __expf(lreluf(as_[s1 * 4 + hd] + adv));
    const float w2 = __expf(lreluf(as_[s2 * 4 + hd] + adv));
    const float w3 = __expf(lreluf(as_[s3 * 4 + hd] + adv));
    const float2 h0 = __half22float2(h[(size_t)s0 * 64 + l]);
    const float2 h1 = __half22float2(h[(size_t)s1 * 64 + l]);
    const float2 h2 = __half22float2(h[(size_t)s2 * 64 + l]);
    const float2 h3 = __half22float2(h[(size_t)s3 * 64 + l]);
    den += (w0 + w1) + (w2 + w3);
    a2.x = fmaf(h0.x, w0, a2.x);
    a2.y = fmaf(h0.y, w0, a2.y);
    a2.x = fmaf(h1.x, w1, a2.x);
    a2.y = fmaf(h1.y, w1, a2.y);
    a2.x = fmaf(h2.x, w2, a2.x);
    a2.y = fmaf(h2.y, w2, a2.y);
    a2.x = fmaf(h3.x, w3, a2.x);
    a2.y = fmaf(h3.y, w3, a2.y);
  }
  for (; e < end; ++e) {
    const int s0 = esrc[e];
    const float w0 = __expf(lreluf(as_[s0 * 4 + hd] + adv));
    const float2 h0 = __half22float2(h[(size_t)s0 * 64 + l]);
    den += w0;
    a2.x = fmaf(h0.x, w0, a2.x);
    a2.y = fmaf(h0.y, w0, a2.y);
  }
  const float inv = 1.0f / (den + 1e-16f);
  const float o0 = a2.x * inv;
  const float o1 = a2.y * inv;
  if (out16) {
    const float2 b = *(const float2*)(bias + l * 2);
    out16[(size_t)wid * 64 + l] = __floats2half2_rn(eluf(o0 + b.x), eluf(o1 + b.y));
  } else {
    outf[(size_t)wid * FEAT + l * 2 + 0] = o0;
    outf[(size_t)wid * FEAT + l * 2 + 1] = o1;
  }
}

// ---------------- FC head: out = elu(acc+b) @ Wfc + bfc ----------------
__global__ __launch_bounds__(256) void fc_kernel(
    const float* __restrict__ acc, const float* __restrict__ bias,
    const float* __restrict__ Wfc, const float* __restrict__ bfc,
    float* __restrict__ out, int n) {
  __shared__ float wl[256];
  __shared__ float bl[128];
  const int t = threadIdx.x;
  wl[t] = Wfc[t & 255];
  if (t < 128) bl[t] = bias[t];
  __syncthreads();
  int idx = blockIdx.x * 256 + t;
  int node = idx >> 5;
  int l = idx & 31;
  if (node >= n) return;
  float4 v = *(const float4*)(acc + (size_t)node * FEAT + l * 4);
  float h0 = eluf(v.x + bl[l * 4 + 0]);
  float h1 = eluf(v.y + bl[l * 4 + 1]);
  float h2 = eluf(v.z + bl[l * 4 + 2]);
  float h3 = eluf(v.w + bl[l * 4 + 3]);
  float s0 = h0 * wl[(l * 4 + 0) * 2 + 0] + h1 * wl[(l * 4 + 1) * 2 + 0] +
             h2 * wl[(l * 4 + 2) * 2 + 0] + h3 * wl[(l * 4 + 3) * 2 + 0];
  float s1 = h0 * wl[(l * 4 + 0) * 2 + 1] + h1 * wl[(l * 4 + 1) * 2 + 1] +
             h2 * wl[(l * 4 + 2) * 2 + 1] + h3 * wl[(l * 4 + 3) * 2 + 1];
#pragma unroll
  for (int o = 16; o >= 1; o >>= 1) {
    s0 += __shfl_xor(s0, o);
    s1 += __shfl_xor(s1, o);
  }
  if (l == 0) {
    out[node * 2 + 0] = s0 + bfc[0];
    out[node * 2 + 1] = s1 + bfc[1];
  }
}

extern "C" void kernel_launch(void* const* d_in, const int* in_sizes, int n_in,
                              void* d_out, int out_size, void* d_ws, size_t ws_size,
                              hipStream_t stream) {
  const float* x   = (const float*)d_in[0];
  const int*   ei  = (const int*)d_in[1];
  const float* W1  = (const float*)d_in[2];
  const float* as1 = (const float*)d_in[3];
  const float* ad1 = (const float*)d_in[4];
  const float* b1  = (const float*)d_in[5];
  const float* W2  = (const float*)d_in[6];
  const float* as2 = (const float*)d_in[7];
  const float* ad2 = (const float*)d_in[8];
  const float* b2  = (const float*)d_in[9];
  const float* Wfc = (const float*)d_in[10];
  const float* bfc = (const float*)d_in[11];
  float* out = (float*)d_out;

  const int N = in_sizes[0] / FEAT;
  const int E = in_sizes[1] / 2;
  const int ET = E + N;

  // workspace layout
  char* ws = (char*)d_ws;
  __half* hraw = (__half*)ws;                               // N*128 fp16
  __half* hin2 = hraw + (size_t)N * FEAT;                   // N*128 fp16
  float* acc   = (float*)(hin2 + (size_t)N * FEAT);         // N*128 f32
  float* asb   = acc + (size_t)N * FEAT;                    // N*4
  float* adb   = asb + (size_t)N * 4;                       // N*4
  __half* bfrag1 = (__half*)(adb + (size_t)N * 4);          // 4*9*64*8 fp16
  __half* bfrag2 = bfrag1 + 4 * 9 * 64 * 8;                 // 4*9*64*8 fp16
  int* cnt     = (int*)(bfrag2 + 4 * 9 * 64 * 8);           // N
  int* pre     = cnt + N;                                   // N
  int* bsum    = pre + N;                                   // 256
  int* row_ptr = bsum + 256;                                // N+1
  int* cursor  = row_ptr + (N + 1);                         // N
  int* esrc    = cursor + N;                                // ET

  const dim3 b256(256);
  const int egrid = (ET + 255) / 256;
  const int ngrid = (N + 255) / 256;
  const int nb = (N + 1023) / 1024;

  // ---- prepack W fragments (both layers) ----
  pack_w_kernel<<<9, b256, 0, stream>>>(W1, as1, ad1, bfrag1);
  pack_w_kernel<<<9, b256, 0, stream>>>(W2, as2, ad2, bfrag2);

  // ---- CSR build ----
  zero_int_kernel<<<ngrid, b256, 0, stream>>>(cnt, N);
  hist_kernel<<<egrid, b256, 0, stream>>>(ei, cnt, E, ET);
  scan1_kernel<<<nb, b256, 0, stream>>>(cnt, pre, bsum, N);
  scan2_kernel<<<1, b256, 0, stream>>>(bsum, nb);
  scan3_kernel<<<ngrid, b256, 0, stream>>>(pre, bsum, row_ptr, cursor, N, ET);
  scatter_kernel<<<egrid, b256, 0, stream>>>(ei, cursor, esrc, E, ET);

  const int ntiles = (N + 15) / 16;
  const int ggrid = (ntiles + 3) / 4;          // 4 waves per block
  const int wgrid = (N * 64 + 255) / 256;      // one wave per node
  const int fgrid = (N * 32 + 255) / 256;

  // ---- layer 1 ----
  gemm_mfma_kernel<true><<<ggrid, b256, 0, stream>>>(x, bfrag1, hraw, asb, adb, N);
  node_gat_kernel<<<wgrid, b256, 0, stream>>>(row_ptr, esrc, asb, adb,
                                              (const __half2*)hraw, b1,
                                              (__half2*)hin2, nullptr, N);

  // ---- layer 2 ----
  gemm_mfma_kernel<false><<<ggrid, b256, 0, stream>>>(hin2, bfrag2, hraw, asb, adb, N);
  node_gat_kernel<<<wgrid, b256, 0, stream>>>(row_ptr, esrc, asb, adb,
                                              (const __half2*)hraw, nullptr,
                                              nullptr, acc, N);

  // ---- fc head ----
  fc_kernel<<<fgrid, b256, 0, stream>>>(acc, b2, Wfc, bfc, out, N);
}

// Round 5
// 294.608 us; speedup vs baseline: 24.2509x; 1.5336x over previous
//
#include <hip/hip_runtime.h>
#include <hip/hip_fp16.h>
#include <math.h>

#define FEAT 128
#define NBLK 256       // blocks for bucket hist/scatter
#define BSHIFT 8       // bucket = dst >> 8 (256 nodes per bucket)

typedef _Float16 f16x8 __attribute__((ext_vector_type(8)));
typedef float f32x4 __attribute__((ext_vector_type(4)));

__device__ __forceinline__ float eluf(float x) {
  return x > 0.0f ? x : (__expf(x) - 1.0f);
}
__device__ __forceinline__ float lreluf(float x) {
  return x > 0.0f ? x : 0.2f * x;
}

// ---------------- generic scan kernels (1024 elems/block) ----------------

__global__ __launch_bounds__(256) void scan1_kernel(const int* __restrict__ cnt,
                                                    int* __restrict__ pre,
                                                    int* __restrict__ bsum, int n) {
  __shared__ int sd[256];
  const int t = threadIdx.x;
  const int idx = blockIdx.x * 1024 + t * 4;
  int4 v = make_int4(0, 0, 0, 0);
  if (idx + 3 < n) {
    v = *(const int4*)(cnt + idx);
  } else {
    if (idx < n)     v.x = cnt[idx];
    if (idx + 1 < n) v.y = cnt[idx + 1];
    if (idx + 2 < n) v.z = cnt[idx + 2];
    if (idx + 3 < n) v.w = cnt[idx + 3];
  }
  const int tsum = v.x + v.y + v.z + v.w;
  sd[t] = tsum;
  __syncthreads();
  for (int o = 1; o < 256; o <<= 1) {
    int x = (t >= o) ? sd[t - o] : 0;
    __syncthreads();
    sd[t] += x;
    __syncthreads();
  }
  const int excl = sd[t] - tsum;
  if (idx < n)     pre[idx]     = excl;
  if (idx + 1 < n) pre[idx + 1] = excl + v.x;
  if (idx + 2 < n) pre[idx + 2] = excl + v.x + v.y;
  if (idx + 3 < n) pre[idx + 3] = excl + v.x + v.y + v.z;
  if (t == 255) bsum[blockIdx.x] = sd[255];
}

__global__ __launch_bounds__(256) void scan2_kernel(int* __restrict__ bsum, int nb) {
  __shared__ int sd[256];
  const int t = threadIdx.x;
  int v = (t < nb) ? bsum[t] : 0;
  sd[t] = v;
  __syncthreads();
  for (int o = 1; o < 256; o <<= 1) {
    int x = (t >= o) ? sd[t - o] : 0;
    __syncthreads();
    sd[t] += x;
    __syncthreads();
  }
  if (t < nb) bsum[t] = sd[t] - v;
}

// ---------------- bucketed CSR build ----------------
// A: per-block LDS histogram over dst buckets -> gh[bucket*NBLK + block]
__global__ __launch_bounds__(256) void bucket_hist_kernel(
    const int* __restrict__ ei, int* __restrict__ gh,
    int E, int ET, int nbuck, int chunk) {
  __shared__ int h[512];
  const int t = threadIdx.x;
  const int b = blockIdx.x;
  h[t] = 0; h[t + 256] = 0;
  __syncthreads();
  const int lo = b * chunk;
  const int hi = min(lo + chunk, ET);
  for (int i = lo + t; i < hi; i += 256) {
    int d = (i < E) ? ei[E + i] : (i - E);
    atomicAdd(&h[d >> BSHIFT], 1);
  }
  __syncthreads();
  for (int k = t; k < nbuck; k += 256) gh[k * NBLK + b] = h[k];
}

// C: scatter (src,dst) pairs into bucket-major, block-exclusive runs
__global__ __launch_bounds__(256) void bucket_scatter_kernel(
    const int* __restrict__ ei, const int* __restrict__ ghp,
    const int* __restrict__ bsum, int2* __restrict__ pairs,
    int E, int ET, int nbuck, int chunk) {
  __shared__ int cur[512];
  const int t = threadIdx.x;
  const int b = blockIdx.x;
  for (int k = t; k < nbuck; k += 256) {
    int idx = k * NBLK + b;
    cur[k] = ghp[idx] + bsum[idx >> 10];
  }
  __syncthreads();
  const int lo = b * chunk;
  const int hi = min(lo + chunk, ET);
  for (int i = lo + t; i < hi; i += 256) {
    int s, d;
    if (i < E) { s = ei[i]; d = ei[E + i]; } else { s = d = i - E; }
    int pos = atomicAdd(&cur[d >> BSHIFT], 1);
    pairs[pos] = make_int2(s, d);
  }
}

// D: per-bucket local counting sort -> row_ptr + esrc
__global__ __launch_bounds__(256) void bucket_finalize_kernel(
    const int2* __restrict__ pairs, const int* __restrict__ ghp,
    const int* __restrict__ bsum, int* __restrict__ row_ptr,
    int* __restrict__ esrc, int N, int ET, int nbuck) {
  __shared__ int hist[256];
  __shared__ int cur[256];
  const int t = threadIdx.x;
  const int k = blockIdx.x;
  const int node0 = k << BSHIFT;
  const int idx0 = k * NBLK;
  const int base = ghp[idx0] + bsum[idx0 >> 10];
  int end;
  if (k + 1 < nbuck) {
    const int idx1 = (k + 1) * NBLK;
    end = ghp[idx1] + bsum[idx1 >> 10];
  } else {
    end = ET;
  }
  hist[t] = 0;
  __syncthreads();
  for (int e = base + t; e < end; e += 256) {
    atomicAdd(&hist[pairs[e].y - node0], 1);
  }
  __syncthreads();
  // exclusive scan of hist[256]
  const int v = hist[t];
  __syncthreads();
  __shared__ int sd[256];
  sd[t] = v;
  __syncthreads();
  for (int o = 1; o < 256; o <<= 1) {
    int x = (t >= o) ? sd[t - o] : 0;
    __syncthreads();
    sd[t] += x;
    __syncthreads();
  }
  const int excl = sd[t] - v;
  if (node0 + t < N) row_ptr[node0 + t] = base + excl;
  cur[t] = excl;
  __syncthreads();
  for (int e = base + t; e < end; e += 256) {
    int2 p = pairs[e];
    int pos = atomicAdd(&cur[p.y - node0], 1);
    esrc[base + pos] = p.x;
  }
  if (k == 0 && t == 0) row_ptr[N] = ET;
}

// ---------------- W fragment prepack ----------------
// frag layout: [kstep(4)][tile(9)][lane(64)][elem(8)] fp16.
// tile t covers cols 16t+0..15 of B' = [W | W@a_src^T | W@a_dst^T | 0-pad].
__global__ __launch_bounds__(256) void pack_w_kernel(
    const float* __restrict__ W, const float* __restrict__ a_src,
    const float* __restrict__ a_dst, __half* __restrict__ frag) {
  int tid = blockIdx.x * 256 + threadIdx.x;
  if (tid >= 4 * 9 * 64) return;
  int lane = tid & 63;
  int tile = (tid >> 6) % 9;
  int ks = tid / (9 * 64);
  int li = lane & 15, hi = lane >> 4;
  int col = tile * 16 + li;
  __half* dst = frag + (size_t)tid * 8;
  for (int i = 0; i < 8; ++i) {
    int k = ks * 32 + hi * 8 + i;
    float v = 0.f;
    if (col < 128) {
      v = W[k * 128 + col];
    } else if (col < 132) {
      int h = col - 128;
      float s = 0.f;
      for (int j = 0; j < 32; ++j) s += W[k * 128 + h * 32 + j] * a_src[h * 32 + j];
      v = s;
    } else if (col < 136) {
      int h = col - 132;
      float s = 0.f;
      for (int j = 0; j < 32; ++j) s += W[k * 128 + h * 32 + j] * a_dst[h * 32 + j];
      v = s;
    }
    dst[i] = __float2half(v);
  }
}

// ---------------- MFMA GEMM: h = in @ W (+ fused alpha columns) ----------------
template <bool F32IN>
__global__ __launch_bounds__(256) void gemm_mfma_kernel(
    const void* __restrict__ in, const __half* __restrict__ frag,
    __half* __restrict__ hout, float* __restrict__ as_out, float* __restrict__ ad_out,
    int nrows) {
  const int wid = (blockIdx.x * 256 + threadIdx.x) >> 6;
  const int lane = threadIdx.x & 63;
  const int li = lane & 15, hi = lane >> 4;
  int row = wid * 16 + li;
  const bool valid = row < nrows;
  if (wid * 16 >= nrows) return;
  if (!valid) row = nrows - 1;  // safe load, stores predicated

  const f16x8* fragv = (const f16x8*)frag;

  f32x4 acc[9];
#pragma unroll
  for (int t = 0; t < 9; ++t) acc[t] = (f32x4){0.f, 0.f, 0.f, 0.f};

#pragma unroll
  for (int ks = 0; ks < 4; ++ks) {
    f16x8 xf;
    if (F32IN) {
      const float* xp = (const float*)in + (size_t)row * FEAT + ks * 32 + hi * 8;
      float4 v0 = *(const float4*)xp;
      float4 v1 = *(const float4*)(xp + 4);
      xf[0] = (_Float16)v0.x; xf[1] = (_Float16)v0.y;
      xf[2] = (_Float16)v0.z; xf[3] = (_Float16)v0.w;
      xf[4] = (_Float16)v1.x; xf[5] = (_Float16)v1.y;
      xf[6] = (_Float16)v1.z; xf[7] = (_Float16)v1.w;
    } else {
      xf = *(const f16x8*)((const __half*)in + (size_t)row * FEAT + ks * 32 + hi * 8);
    }
#pragma unroll
    for (int t = 0; t < 9; ++t) {
      f16x8 wf = fragv[(ks * 9 + t) * 64 + lane];
      acc[t] = __builtin_amdgcn_mfma_f32_16x16x32_f16(wf, xf, acc[t], 0, 0, 0);
    }
  }

  if (!valid) return;
#pragma unroll
  for (int t = 0; t < 8; ++t) {
    union { __half2 h[2]; uint2 u; } pk;
    pk.h[0] = __floats2half2_rn(acc[t][0], acc[t][1]);
    pk.h[1] = __floats2half2_rn(acc[t][2], acc[t][3]);
    *(uint2*)(hout + (size_t)row * FEAT + t * 16 + hi * 4) = pk.u;
  }
  if (hi == 0) *(float4*)(as_out + row * 4) = make_float4(acc[8][0], acc[8][1], acc[8][2], acc[8][3]);
  if (hi == 1) *(float4*)(ad_out + row * 4) = make_float4(acc[8][0], acc[8][1], acc[8][2], acc[8][3]);
}

// ---------------- per-node softmax + aggregation ----------------
__global__ __launch_bounds__(256) void node_gat_kernel(
    const int* __restrict__ row_ptr, const int* __restrict__ esrc,
    const float* __restrict__ as_, const float* __restrict__ ad_,
    const __half2* __restrict__ h, const float* __restrict__ bias,
    __half2* __restrict__ out16, float* __restrict__ outf, int n) {
  const int wid = (blockIdx.x * 256 + threadIdx.x) >> 6;
  if (wid >= n) return;
  const int l = threadIdx.x & 63;
  const int begin = row_ptr[wid];
  const int end = row_ptr[wid + 1];
  const int hd = l >> 4;
  const float adv = ad_[wid * 4 + hd];

  float2 a2 = make_float2(0.f, 0.f);
  float den = 0.f;
  int e = begin;
  for (; e + 3 < end; e += 4) {
    const int s0 = esrc[e + 0];
    const int s1 = esrc[e + 1];
    const int s2 = esrc[e + 2];
    const int s3 = esrc[e + 3];
    const float w0 = __expf(lreluf(as_[s0 * 4 + hd] + adv));
    const float w1 = __expf(lreluf(as_[s1 * 4 + hd] + adv));
    const float w2 = __expf(lreluf(as_[s2 * 4 + hd] + adv));
    const float w3 = __expf(lreluf(as_[s3 * 4 + hd] + adv));
    const float2 h0 = __half22float2(h[(size_t)s0 * 64 + l]);
    const float2 h1 = __half22float2(h[(size_t)s1 * 64 + l]);
    const float2 h2 = __half22float2(h[(size_t)s2 * 64 + l]);
    const float2 h3 = __half22float2(h[(size_t)s3 * 64 + l]);
    den += (w0 + w1) + (w2 + w3);
    a2.x = fmaf(h0.x, w0, a2.x);
    a2.y = fmaf(h0.y, w0, a2.y);
    a2.x = fmaf(h1.x, w1, a2.x);
    a2.y = fmaf(h1.y, w1, a2.y);
    a2.x = fmaf(h2.x, w2, a2.x);
    a2.y = fmaf(h2.y, w2, a2.y);
    a2.x = fmaf(h3.x, w3, a2.x);
    a2.y = fmaf(h3.y, w3, a2.y);
  }
  for (; e < end; ++e) {
    const int s0 = esrc[e];
    const float w0 = __expf(lreluf(as_[s0 * 4 + hd] + adv));
    const float2 h0 = __half22float2(h[(size_t)s0 * 64 + l]);
    den += w0;
    a2.x = fmaf(h0.x, w0, a2.x);
    a2.y = fmaf(h0.y, w0, a2.y);
  }
  const float inv = 1.0f / (den + 1e-16f);
  const float o0 = a2.x * inv;
  const float o1 = a2.y * inv;
  if (out16) {
    const float2 b = *(const float2*)(bias + l * 2);
    out16[(size_t)wid * 64 + l] = __floats2half2_rn(eluf(o0 + b.x), eluf(o1 + b.y));
  } else {
    outf[(size_t)wid * FEAT + l * 2 + 0] = o0;
    outf[(size_t)wid * FEAT + l * 2 + 1] = o1;
  }
}

// ---------------- FC head: out = elu(acc+b) @ Wfc + bfc ----------------
__global__ __launch_bounds__(256) void fc_kernel(
    const float* __restrict__ acc, const float* __restrict__ bias,
    const float* __restrict__ Wfc, const float* __restrict__ bfc,
    float* __restrict__ out, int n) {
  __shared__ float wl[256];
  __shared__ float bl[128];
  const int t = threadIdx.x;
  wl[t] = Wfc[t & 255];
  if (t < 128) bl[t] = bias[t];
  __syncthreads();
  int idx = blockIdx.x * 256 + t;
  int node = idx >> 5;
  int l = idx & 31;
  if (node >= n) return;
  float4 v = *(const float4*)(acc + (size_t)node * FEAT + l * 4);
  float h0 = eluf(v.x + bl[l * 4 + 0]);
  float h1 = eluf(v.y + bl[l * 4 + 1]);
  float h2 = eluf(v.z + bl[l * 4 + 2]);
  float h3 = eluf(v.w + bl[l * 4 + 3]);
  float s0 = h0 * wl[(l * 4 + 0) * 2 + 0] + h1 * wl[(l * 4 + 1) * 2 + 0] +
             h2 * wl[(l * 4 + 2) * 2 + 0] + h3 * wl[(l * 4 + 3) * 2 + 0];
  float s1 = h0 * wl[(l * 4 + 0) * 2 + 1] + h1 * wl[(l * 4 + 1) * 2 + 1] +
             h2 * wl[(l * 4 + 2) * 2 + 1] + h3 * wl[(l * 4 + 3) * 2 + 1];
#pragma unroll
  for (int o = 16; o >= 1; o >>= 1) {
    s0 += __shfl_xor(s0, o);
    s1 += __shfl_xor(s1, o);
  }
  if (l == 0) {
    out[node * 2 + 0] = s0 + bfc[0];
    out[node * 2 + 1] = s1 + bfc[1];
  }
}

extern "C" void kernel_launch(void* const* d_in, const int* in_sizes, int n_in,
                              void* d_out, int out_size, void* d_ws, size_t ws_size,
                              hipStream_t stream) {
  const float* x   = (const float*)d_in[0];
  const int*   ei  = (const int*)d_in[1];
  const float* W1  = (const float*)d_in[2];
  const float* as1 = (const float*)d_in[3];
  const float* ad1 = (const float*)d_in[4];
  const float* b1  = (const float*)d_in[5];
  const float* W2  = (const float*)d_in[6];
  const float* as2 = (const float*)d_in[7];
  const float* ad2 = (const float*)d_in[8];
  const float* b2  = (const float*)d_in[9];
  const float* Wfc = (const float*)d_in[10];
  const float* bfc = (const float*)d_in[11];
  float* out = (float*)d_out;

  const int N = in_sizes[0] / FEAT;
  const int E = in_sizes[1] / 2;
  const int ET = E + N;
  const int nbuck = (N + 255) >> BSHIFT;     // buckets of 256 nodes
  const int NN = nbuck * NBLK;               // gh array length
  const int chunk = (ET + NBLK - 1) / NBLK;

  // workspace layout
  char* ws = (char*)d_ws;
  __half* hraw = (__half*)ws;                               // N*128 fp16
  __half* hin2 = hraw + (size_t)N * FEAT;                   // N*128 fp16
  float* acc   = (float*)(hin2 + (size_t)N * FEAT);         // N*128 f32
  float* asb   = acc + (size_t)N * FEAT;                    // N*4
  float* adb   = asb + (size_t)N * 4;                       // N*4
  __half* bfrag1 = (__half*)(adb + (size_t)N * 4);          // 4*9*64*8 fp16
  __half* bfrag2 = bfrag1 + 4 * 9 * 64 * 8;                 // 4*9*64*8 fp16
  int* bsum    = (int*)(bfrag2 + 4 * 9 * 64 * 8);           // 256
  int* row_ptr = bsum + 256;                                // N+1
  int* esrc    = row_ptr + (N + 1);                         // ET
  // CSR-build scratch aliased into acc region (dead until layer-2 node_gat):
  int* gh    = (int*)acc;                                   // NN (16B aligned)
  int* ghp   = gh + NN;                                     // NN
  int2* pairs = (int2*)(ghp + NN);                          // ET (8B aligned)

  const dim3 b256(256);
  const int nb = (NN + 1023) / 1024;

  // ---- prepack W fragments ----
  pack_w_kernel<<<9, b256, 0, stream>>>(W1, as1, ad1, bfrag1);
  pack_w_kernel<<<9, b256, 0, stream>>>(W2, as2, ad2, bfrag2);

  // ---- bucketed CSR build ----
  bucket_hist_kernel<<<NBLK, b256, 0, stream>>>(ei, gh, E, ET, nbuck, chunk);
  scan1_kernel<<<nb, b256, 0, stream>>>(gh, ghp, bsum, NN);
  scan2_kernel<<<1, b256, 0, stream>>>(bsum, nb);
  bucket_scatter_kernel<<<NBLK, b256, 0, stream>>>(ei, ghp, bsum, pairs, E, ET, nbuck, chunk);
  bucket_finalize_kernel<<<nbuck, b256, 0, stream>>>(pairs, ghp, bsum, row_ptr, esrc, N, ET, nbuck);

  const int ntiles = (N + 15) / 16;
  const int ggrid = (ntiles + 3) / 4;
  const int wgrid = (N * 64 + 255) / 256;
  const int fgrid = (N * 32 + 255) / 256;

  // ---- layer 1 ----
  gemm_mfma_kernel<true><<<ggrid, b256, 0, stream>>>(x, bfrag1, hraw, asb, adb, N);
  node_gat_kernel<<<wgrid, b256, 0, stream>>>(row_ptr, esrc, asb, adb,
                                              (const __half2*)hraw, b1,
                                              (__half2*)hin2, nullptr, N);

  // ---- layer 2 ----
  gemm_mfma_kernel<false><<<ggrid, b256, 0, stream>>>(hin2, bfrag2, hraw, asb, adb, N);
  node_gat_kernel<<<wgrid, b256, 0, stream>>>(row_ptr, esrc, asb, adb,
                                              (const __half2*)hraw, nullptr,
                                              nullptr, acc, N);

  // ---- fc head ----
  fc_kernel<<<fgrid, b256, 0, stream>>>(acc, b2, Wfc, bfc, out, N);
}

// Round 6
// 268.546 us; speedup vs baseline: 26.6044x; 1.0970x over previous
//
#include <hip/hip_runtime.h>
#include <hip/hip_fp16.h>
#include <math.h>

#define FEAT 128
#define NBLK 256       // blocks for bucket hist/scatter
#define BSHIFT 8       // bucket = dst >> 8 (256 nodes per bucket)

typedef _Float16 f16x8 __attribute__((ext_vector_type(8)));
typedef float f32x4 __attribute__((ext_vector_type(4)));

__device__ __forceinline__ float eluf(float x) {
  return x > 0.0f ? x : (__expf(x) - 1.0f);
}

// ---------------- generic scan kernels (1024 elems/block) ----------------

__global__ __launch_bounds__(256) void scan1_kernel(const int* __restrict__ cnt,
                                                    int* __restrict__ pre,
                                                    int* __restrict__ bsum, int n) {
  __shared__ int sd[256];
  const int t = threadIdx.x;
  const int idx = blockIdx.x * 1024 + t * 4;
  int4 v = make_int4(0, 0, 0, 0);
  if (idx + 3 < n) {
    v = *(const int4*)(cnt + idx);
  } else {
    if (idx < n)     v.x = cnt[idx];
    if (idx + 1 < n) v.y = cnt[idx + 1];
    if (idx + 2 < n) v.z = cnt[idx + 2];
    if (idx + 3 < n) v.w = cnt[idx + 3];
  }
  const int tsum = v.x + v.y + v.z + v.w;
  sd[t] = tsum;
  __syncthreads();
  for (int o = 1; o < 256; o <<= 1) {
    int x = (t >= o) ? sd[t - o] : 0;
    __syncthreads();
    sd[t] += x;
    __syncthreads();
  }
  const int excl = sd[t] - tsum;
  if (idx < n)     pre[idx]     = excl;
  if (idx + 1 < n) pre[idx + 1] = excl + v.x;
  if (idx + 2 < n) pre[idx + 2] = excl + v.x + v.y;
  if (idx + 3 < n) pre[idx + 3] = excl + v.x + v.y + v.z;
  if (t == 255) bsum[blockIdx.x] = sd[255];
}

__global__ __launch_bounds__(256) void scan2_kernel(int* __restrict__ bsum, int nb) {
  __shared__ int sd[256];
  const int t = threadIdx.x;
  int v = (t < nb) ? bsum[t] : 0;
  sd[t] = v;
  __syncthreads();
  for (int o = 1; o < 256; o <<= 1) {
    int x = (t >= o) ? sd[t - o] : 0;
    __syncthreads();
    sd[t] += x;
    __syncthreads();
  }
  if (t < nb) bsum[t] = sd[t] - v;
}

// ---------------- bucketed CSR build ----------------
// A: per-block LDS histogram over dst buckets -> gh[bucket*NBLK + block]
__global__ __launch_bounds__(256) void bucket_hist_kernel(
    const int* __restrict__ ei, int* __restrict__ gh,
    int E, int ET, int nbuck, int chunk) {
  __shared__ int h[512];
  const int t = threadIdx.x;
  const int b = blockIdx.x;
  h[t] = 0; h[t + 256] = 0;
  __syncthreads();
  const int lo = b * chunk;
  const int hi = min(lo + chunk, ET);
  for (int i = lo + t; i < hi; i += 256) {
    int d = (i < E) ? ei[E + i] : (i - E);
    atomicAdd(&h[d >> BSHIFT], 1);
  }
  __syncthreads();
  for (int k = t; k < nbuck; k += 256) gh[k * NBLK + b] = h[k];
}

// C: scatter packed (src<<8 | dst&255) into bucket-major, block-exclusive runs
__global__ __launch_bounds__(256) void bucket_scatter_kernel(
    const int* __restrict__ ei, const int* __restrict__ ghp,
    const int* __restrict__ bsum, unsigned* __restrict__ pairs,
    int E, int ET, int nbuck, int chunk) {
  __shared__ int cur[512];
  const int t = threadIdx.x;
  const int b = blockIdx.x;
  for (int k = t; k < nbuck; k += 256) {
    int idx = k * NBLK + b;
    cur[k] = ghp[idx] + bsum[idx >> 10];
  }
  __syncthreads();
  const int lo = b * chunk;
  const int hi = min(lo + chunk, ET);
  for (int i = lo + t; i < hi; i += 256) {
    int s, d;
    if (i < E) { s = ei[i]; d = ei[E + i]; } else { s = d = i - E; }
    int pos = atomicAdd(&cur[d >> BSHIFT], 1);
    pairs[pos] = ((unsigned)s << 8) | (unsigned)(d & 255);
  }
}

// D: per-bucket local counting sort -> row_ptr + esrc
__global__ __launch_bounds__(256) void bucket_finalize_kernel(
    const unsigned* __restrict__ pairs, const int* __restrict__ ghp,
    const int* __restrict__ bsum, int* __restrict__ row_ptr,
    int* __restrict__ esrc, int N, int ET, int nbuck) {
  __shared__ int hist[256];
  __shared__ int cur[256];
  __shared__ int sd[256];
  const int t = threadIdx.x;
  const int k = blockIdx.x;
  const int node0 = k << BSHIFT;
  const int idx0 = k * NBLK;
  const int base = ghp[idx0] + bsum[idx0 >> 10];
  int end;
  if (k + 1 < nbuck) {
    const int idx1 = (k + 1) * NBLK;
    end = ghp[idx1] + bsum[idx1 >> 10];
  } else {
    end = ET;
  }
  hist[t] = 0;
  __syncthreads();
  for (int e = base + t; e < end; e += 256) {
    atomicAdd(&hist[pairs[e] & 255u], 1);
  }
  __syncthreads();
  const int v = hist[t];
  __syncthreads();
  sd[t] = v;
  __syncthreads();
  for (int o = 1; o < 256; o <<= 1) {
    int x = (t >= o) ? sd[t - o] : 0;
    __syncthreads();
    sd[t] += x;
    __syncthreads();
  }
  const int excl = sd[t] - v;
  if (node0 + t < N) row_ptr[node0 + t] = base + excl;
  cur[t] = excl;
  __syncthreads();
  for (int e = base + t; e < end; e += 256) {
    unsigned p = pairs[e];
    int pos = atomicAdd(&cur[p & 255u], 1);
    esrc[base + pos] = (int)(p >> 8);
  }
  if (k == 0 && t == 0) row_ptr[N] = ET;
}

// ---------------- W fragment prepack ----------------
// frag layout: [kstep(4)][tile(9)][lane(64)][elem(8)] fp16.
// tile t covers cols 16t+0..15 of B' = [W | W@a_src^T | W@a_dst^T | 0-pad].
__global__ __launch_bounds__(256) void pack_w_kernel(
    const float* __restrict__ W, const float* __restrict__ a_src,
    const float* __restrict__ a_dst, __half* __restrict__ frag) {
  int tid = blockIdx.x * 256 + threadIdx.x;
  if (tid >= 4 * 9 * 64) return;
  int lane = tid & 63;
  int tile = (tid >> 6) % 9;
  int ks = tid / (9 * 64);
  int li = lane & 15, hi = lane >> 4;
  int col = tile * 16 + li;
  __half* dst = frag + (size_t)tid * 8;
  for (int i = 0; i < 8; ++i) {
    int k = ks * 32 + hi * 8 + i;
    float v = 0.f;
    if (col < 128) {
      v = W[k * 128 + col];
    } else if (col < 132) {
      int h = col - 128;
      float s = 0.f;
      for (int j = 0; j < 32; ++j) s += W[k * 128 + h * 32 + j] * a_src[h * 32 + j];
      v = s;
    } else if (col < 136) {
      int h = col - 132;
      float s = 0.f;
      for (int j = 0; j < 32; ++j) s += W[k * 128 + h * 32 + j] * a_dst[h * 32 + j];
      v = s;
    }
    dst[i] = __float2half(v);
  }
}

// ---------------- MFMA GEMM: h = in @ W (+ fused alpha columns) ----------------
template <bool F32IN>
__global__ __launch_bounds__(256) void gemm_mfma_kernel(
    const void* __restrict__ in, const __half* __restrict__ frag,
    __half* __restrict__ hout, float* __restrict__ as_out, float* __restrict__ ad_out,
    int nrows) {
  const int wid = (blockIdx.x * 256 + threadIdx.x) >> 6;
  const int lane = threadIdx.x & 63;
  const int li = lane & 15, hi = lane >> 4;
  int row = wid * 16 + li;
  const bool valid = row < nrows;
  if (wid * 16 >= nrows) return;
  if (!valid) row = nrows - 1;  // safe load, stores predicated

  const f16x8* fragv = (const f16x8*)frag;

  f32x4 acc[9];
#pragma unroll
  for (int t = 0; t < 9; ++t) acc[t] = (f32x4){0.f, 0.f, 0.f, 0.f};

#pragma unroll
  for (int ks = 0; ks < 4; ++ks) {
    f16x8 xf;
    if (F32IN) {
      const float* xp = (const float*)in + (size_t)row * FEAT + ks * 32 + hi * 8;
      float4 v0 = *(const float4*)xp;
      float4 v1 = *(const float4*)(xp + 4);
      xf[0] = (_Float16)v0.x; xf[1] = (_Float16)v0.y;
      xf[2] = (_Float16)v0.z; xf[3] = (_Float16)v0.w;
      xf[4] = (_Float16)v1.x; xf[5] = (_Float16)v1.y;
      xf[6] = (_Float16)v1.z; xf[7] = (_Float16)v1.w;
    } else {
      xf = *(const f16x8*)((const __half*)in + (size_t)row * FEAT + ks * 32 + hi * 8);
    }
#pragma unroll
    for (int t = 0; t < 9; ++t) {
      f16x8 wf = fragv[(ks * 9 + t) * 64 + lane];
      acc[t] = __builtin_amdgcn_mfma_f32_16x16x32_f16(wf, xf, acc[t], 0, 0, 0);
    }
  }

  if (!valid) return;
#pragma unroll
  for (int t = 0; t < 8; ++t) {
    union { __half2 h[2]; uint2 u; } pk;
    pk.h[0] = __floats2half2_rn(acc[t][0], acc[t][1]);
    pk.h[1] = __floats2half2_rn(acc[t][2], acc[t][3]);
    *(uint2*)(hout + (size_t)row * FEAT + t * 16 + hi * 4) = pk.u;
  }
  if (hi == 0) *(float4*)(as_out + row * 4) = make_float4(acc[8][0], acc[8][1], acc[8][2], acc[8][3]);
  if (hi == 1) *(float4*)(ad_out + row * 4) = make_float4(acc[8][0], acc[8][1], acc[8][2], acc[8][3]);
}

// ---------------- per-node softmax + aggregation ----------------
// One wave per node; lane l owns features [2l,2l+1]; head = l>>4.
// MODE 0: write fp16 elu(agg + bias) (next GEMM's input).
// MODE 1: fused FC head -> out[node*2 + {0,1}] = elu(agg+bias) @ Wfc + bfc.
// 8-deep edge chunks: stage wave-uniform srcs, issue all gathers before compute.
template <int MODE>
__global__ __launch_bounds__(256) void node_gat_kernel(
    const int* __restrict__ row_ptr, const int* __restrict__ esrc,
    const float* __restrict__ as_, const float* __restrict__ ad_,
    const __half2* __restrict__ h, const float* __restrict__ bias,
    __half2* __restrict__ out16, const float* __restrict__ fcw,
    const float* __restrict__ fcb, float* __restrict__ outf, int n) {
  const int wid = (blockIdx.x * 256 + threadIdx.x) >> 6;
  if (wid >= n) return;
  const int l = threadIdx.x & 63;
  const int begin = row_ptr[wid];
  const int end = row_ptr[wid + 1];
  const int hd = l >> 4;
  const float adv = ad_[wid * 4 + hd];

  float2 a2 = make_float2(0.f, 0.f);
  float den = 0.f;
  int e = begin;

  for (; e + 7 < end; e += 8) {
    int s[8];
#pragma unroll
    for (int i = 0; i < 8; ++i) s[i] = esrc[e + i];       // wave-uniform -> SGPR
    float as8[8];
#pragma unroll
    for (int i = 0; i < 8; ++i) as8[i] = as_[s[i] * 4 + hd];
    float2 hv[8];
#pragma unroll
    for (int i = 0; i < 8; ++i) hv[i] = __half22float2(h[(size_t)s[i] * 64 + l]);
#pragma unroll
    for (int i = 0; i < 8; ++i) {
      const float x = as8[i] + adv;
      const float w = __expf(fmaxf(x, 0.2f * x));
      den += w;
      a2.x = fmaf(hv[i].x, w, a2.x);
      a2.y = fmaf(hv[i].y, w, a2.y);
    }
  }
  for (; e + 3 < end; e += 4) {
    int s[4];
#pragma unroll
    for (int i = 0; i < 4; ++i) s[i] = esrc[e + i];
    float as4[4];
#pragma unroll
    for (int i = 0; i < 4; ++i) as4[i] = as_[s[i] * 4 + hd];
    float2 hv[4];
#pragma unroll
    for (int i = 0; i < 4; ++i) hv[i] = __half22float2(h[(size_t)s[i] * 64 + l]);
#pragma unroll
    for (int i = 0; i < 4; ++i) {
      const float x = as4[i] + adv;
      const float w = __expf(fmaxf(x, 0.2f * x));
      den += w;
      a2.x = fmaf(hv[i].x, w, a2.x);
      a2.y = fmaf(hv[i].y, w, a2.y);
    }
  }
  for (; e < end; ++e) {
    const int s0 = esrc[e];
    const float x = as_[s0 * 4 + hd] + adv;
    const float w = __expf(fmaxf(x, 0.2f * x));
    const float2 h0 = __half22float2(h[(size_t)s0 * 64 + l]);
    den += w;
    a2.x = fmaf(h0.x, w, a2.x);
    a2.y = fmaf(h0.y, w, a2.y);
  }

  const float inv = 1.0f / (den + 1e-16f);
  const float o0 = a2.x * inv;
  const float o1 = a2.y * inv;
  const float2 b = *(const float2*)(bias + l * 2);
  if (MODE == 0) {
    out16[(size_t)wid * 64 + l] = __floats2half2_rn(eluf(o0 + b.x), eluf(o1 + b.y));
  } else {
    // fused FC head: feats 2l,2l+1 -> Wfc rows; 64-lane reduce
    const float e0 = eluf(o0 + b.x);
    const float e1 = eluf(o1 + b.y);
    const float4 w4 = *(const float4*)(fcw + l * 4);  // Wfc[2l][0..1], Wfc[2l+1][0..1]
    float s0 = e0 * w4.x + e1 * w4.z;
    float s1 = e0 * w4.y + e1 * w4.w;
#pragma unroll
    for (int o = 32; o >= 1; o >>= 1) {
      s0 += __shfl_xor(s0, o);
      s1 += __shfl_xor(s1, o);
    }
    if (l == 0) {
      *(float2*)(outf + (size_t)wid * 2) = make_float2(s0 + fcb[0], s1 + fcb[1]);
    }
  }
}

extern "C" void kernel_launch(void* const* d_in, const int* in_sizes, int n_in,
                              void* d_out, int out_size, void* d_ws, size_t ws_size,
                              hipStream_t stream) {
  const float* x   = (const float*)d_in[0];
  const int*   ei  = (const int*)d_in[1];
  const float* W1  = (const float*)d_in[2];
  const float* as1 = (const float*)d_in[3];
  const float* ad1 = (const float*)d_in[4];
  const float* b1  = (const float*)d_in[5];
  const float* W2  = (const float*)d_in[6];
  const float* as2 = (const float*)d_in[7];
  const float* ad2 = (const float*)d_in[8];
  const float* b2  = (const float*)d_in[9];
  const float* Wfc = (const float*)d_in[10];
  const float* bfc = (const float*)d_in[11];
  float* out = (float*)d_out;

  const int N = in_sizes[0] / FEAT;
  const int E = in_sizes[1] / 2;
  const int ET = E + N;
  const int nbuck = (N + 255) >> BSHIFT;     // buckets of 256 nodes
  const int NN = nbuck * NBLK;               // gh array length
  const int chunk = (ET + NBLK - 1) / NBLK;

  // workspace layout
  char* ws = (char*)d_ws;
  __half* hraw = (__half*)ws;                               // N*128 fp16
  __half* hin2 = hraw + (size_t)N * FEAT;                   // N*128 fp16
  float* acc   = (float*)(hin2 + (size_t)N * FEAT);         // N*128 f32 (CSR scratch)
  float* asb   = acc + (size_t)N * FEAT;                    // N*4
  float* adb   = asb + (size_t)N * 4;                       // N*4
  __half* bfrag1 = (__half*)(adb + (size_t)N * 4);          // 4*9*64*8 fp16
  __half* bfrag2 = bfrag1 + 4 * 9 * 64 * 8;                 // 4*9*64*8 fp16
  int* bsum    = (int*)(bfrag2 + 4 * 9 * 64 * 8);           // 256
  int* row_ptr = bsum + 256;                                // N+1
  int* esrc    = row_ptr + (N + 1);                         // ET
  // CSR-build scratch aliased into acc region (dead after finalize):
  int* gh    = (int*)acc;                                   // NN
  int* ghp   = gh + NN;                                     // NN
  unsigned* pairs = (unsigned*)(ghp + NN);                  // ET

  const dim3 b256(256);
  const int nb = (NN + 1023) / 1024;

  // ---- prepack W fragments ----
  pack_w_kernel<<<9, b256, 0, stream>>>(W1, as1, ad1, bfrag1);
  pack_w_kernel<<<9, b256, 0, stream>>>(W2, as2, ad2, bfrag2);

  // ---- bucketed CSR build ----
  bucket_hist_kernel<<<NBLK, b256, 0, stream>>>(ei, gh, E, ET, nbuck, chunk);
  scan1_kernel<<<nb, b256, 0, stream>>>(gh, ghp, bsum, NN);
  scan2_kernel<<<1, b256, 0, stream>>>(bsum, nb);
  bucket_scatter_kernel<<<NBLK, b256, 0, stream>>>(ei, ghp, bsum, pairs, E, ET, nbuck, chunk);
  bucket_finalize_kernel<<<nbuck, b256, 0, stream>>>(pairs, ghp, bsum, row_ptr, esrc, N, ET, nbuck);

  const int ntiles = (N + 15) / 16;
  const int ggrid = (ntiles + 3) / 4;
  const int wgrid = (N * 64 + 255) / 256;

  // ---- layer 1 ----
  gemm_mfma_kernel<true><<<ggrid, b256, 0, stream>>>(x, bfrag1, hraw, asb, adb, N);
  node_gat_kernel<0><<<wgrid, b256, 0, stream>>>(row_ptr, esrc, asb, adb,
                                                 (const __half2*)hraw, b1,
                                                 (__half2*)hin2, nullptr, nullptr, nullptr, N);

  // ---- layer 2 (FC head fused) ----
  gemm_mfma_kernel<false><<<ggrid, b256, 0, stream>>>(hin2, bfrag2, hraw, asb, adb, N);
  node_gat_kernel<1><<<wgrid, b256, 0, stream>>>(row_ptr, esrc, asb, adb,
                                                 (const __half2*)hraw, b2,
                                                 nullptr, Wfc, bfc, out, N);
}